// Round 1
// baseline (1124.698 us; speedup 1.0000x reference)
//
#include <hip/hip_runtime.h>

// FixSetLinearAttention: B=8 T=2048 C=768 NH=12 hs=64 Lmin=16, 255 segments + tail.
// Pipeline: split-bf16 qkv GEMM (exp-safe) -> on-the-fly outer-product GEMM for v
// -> hierarchical segment sums -> fp32 fused attention -> bf16 proj GEMM.
// Workspace required: ~248 MB.

typedef __bf16 bf16x8 __attribute__((ext_vector_type(8)));
typedef __bf16 bf16x4 __attribute__((ext_vector_type(4)));
typedef float  f32x4  __attribute__((ext_vector_type(4)));

#define DEV __device__ __forceinline__

DEV float hsum4(f32x4 v) { return v[0] + v[1] + v[2] + v[3]; }

// ---------------- prep: f32 -> bf16 (hi) + residual (lo) ----------------
__global__ __launch_bounds__(256) void k_split(const float* __restrict__ in,
                                               __bf16* __restrict__ hi,
                                               __bf16* __restrict__ lo, int n4) {
  int i = blockIdx.x * 256 + threadIdx.x;
  if (i >= n4) return;
  f32x4 x = ((const f32x4*)in)[i];
  bf16x4 h, l;
#pragma unroll
  for (int c = 0; c < 4; ++c) {
    __bf16 hh = (__bf16)x[c];
    h[c] = hh;
    l[c] = (__bf16)(x[c] - (float)hh);
  }
  ((bf16x4*)hi)[i] = h;
  ((bf16x4*)lo)[i] = l;
}

__global__ __launch_bounds__(256) void k_cast(const float* __restrict__ in,
                                              __bf16* __restrict__ outb, int n4) {
  int i = blockIdx.x * 256 + threadIdx.x;
  if (i >= n4) return;
  f32x4 v = ((const f32x4*)in)[i];
  bf16x4 o;
#pragma unroll
  for (int c = 0; c < 4; ++c) o[c] = (__bf16)v[c];
  ((bf16x4*)outb)[i] = o;
}

// ---------------- qkv GEMM: C = A @ B^T, split-bf16 (hh + hl + lh) ----------------
// A = x (16384 x 768), B = Wqkv (2304 x 768). Scattered store into q/k (f32) and v0 (bf16)
// in (b, h, t, d) layout.
__global__ __launch_bounds__(256, 2) void k_gemm_qkv(
    const __bf16* __restrict__ Ah, const __bf16* __restrict__ Al,
    const __bf16* __restrict__ Bh, const __bf16* __restrict__ Bl,
    float* __restrict__ qo, float* __restrict__ ko, __bf16* __restrict__ v0o) {
  __shared__ __bf16 sAh[128][64], sAl[128][64], sBh[128][64], sBl[128][64];
  const int K = 768;
  int tid = threadIdx.x, lane = tid & 63, wave = tid >> 6;
  int wr = wave >> 1, wc = wave & 1;
  int n0 = blockIdx.x * 128, m0 = blockIdx.y * 128;
  f32x4 acc[4][4];
#pragma unroll
  for (int a = 0; a < 4; ++a)
#pragma unroll
    for (int b = 0; b < 4; ++b) acc[a][b] = f32x4{0.f, 0.f, 0.f, 0.f};
  int srow = tid >> 3, schunk = tid & 7;
  for (int k0 = 0; k0 < K; k0 += 64) {
    __syncthreads();
#pragma unroll
    for (int r = 0; r < 4; ++r) {
      int row = srow + r * 32;
      int dst = (schunk ^ (row & 7)) << 3;  // XOR 16B-chunk swizzle
      size_t asrc = (size_t)(m0 + row) * K + k0 + (schunk << 3);
      size_t bsrc = (size_t)(n0 + row) * K + k0 + (schunk << 3);
      *(bf16x8*)&sAh[row][dst] = *(const bf16x8*)&Ah[asrc];
      *(bf16x8*)&sAl[row][dst] = *(const bf16x8*)&Al[asrc];
      *(bf16x8*)&sBh[row][dst] = *(const bf16x8*)&Bh[bsrc];
      *(bf16x8*)&sBl[row][dst] = *(const bf16x8*)&Bl[bsrc];
    }
    __syncthreads();
#pragma unroll
    for (int kk = 0; kk < 2; ++kk) {
      int kc = kk * 4 + (lane >> 4);
      bf16x8 ah[4], al[4], bh[4], bl[4];
#pragma unroll
      for (int mf = 0; mf < 4; ++mf) {
        int row = wr * 64 + mf * 16 + (lane & 15);
        int cc = (kc ^ (row & 7)) << 3;
        ah[mf] = *(const bf16x8*)&sAh[row][cc];
        al[mf] = *(const bf16x8*)&sAl[row][cc];
      }
#pragma unroll
      for (int nf = 0; nf < 4; ++nf) {
        int row = wc * 64 + nf * 16 + (lane & 15);
        int cc = (kc ^ (row & 7)) << 3;
        bh[nf] = *(const bf16x8*)&sBh[row][cc];
        bl[nf] = *(const bf16x8*)&sBl[row][cc];
      }
#pragma unroll
      for (int mf = 0; mf < 4; ++mf)
#pragma unroll
        for (int nf = 0; nf < 4; ++nf) {
          acc[mf][nf] = __builtin_amdgcn_mfma_f32_16x16x32_bf16(ah[mf], bh[nf], acc[mf][nf], 0, 0, 0);
          acc[mf][nf] = __builtin_amdgcn_mfma_f32_16x16x32_bf16(ah[mf], bl[nf], acc[mf][nf], 0, 0, 0);
          acc[mf][nf] = __builtin_amdgcn_mfma_f32_16x16x32_bf16(al[mf], bh[nf], acc[mf][nf], 0, 0, 0);
        }
    }
  }
  int sec = n0 / 768;  // block fully inside one of q/k/v0 (768 % 128 == 0)
  int nb = n0 - sec * 768;
#pragma unroll
  for (int mf = 0; mf < 4; ++mf)
#pragma unroll
    for (int nf = 0; nf < 4; ++nf)
#pragma unroll
      for (int r = 0; r < 4; ++r) {
        int m = m0 + wr * 64 + mf * 16 + ((lane >> 4) << 2) + r;
        int n = nb + wc * 64 + nf * 16 + (lane & 15);
        int b = m >> 11, t = m & 2047;
        int h = n >> 6, d = n & 63;
        size_t idx = (((size_t)b * 12 + h) * 2048 + t) * 64 + d;
        float val = acc[mf][nf][r];
        if (sec == 0) qo[idx] = val;
        else if (sec == 1) ko[idx] = val;
        else v0o[idx] = (__bf16)val;
      }
}

// ---------------- v = (k (x) v0) @ Wv^T + bv, A built on the fly ----------------
// 256 token-rows per block, 4 waves x (64 rows x 64 cols). K = 4096 = 64 i-blocks.
__global__ __launch_bounds__(256, 2) void k_veins(
    const float* __restrict__ kmat, const __bf16* __restrict__ v0g,
    const __bf16* __restrict__ Wvb, const float* __restrict__ bv,
    __bf16* __restrict__ vout) {
  __shared__ __bf16 kv[256][72];   // k tile bf16, padded (scalar reads)
  __shared__ __bf16 v0s[256][64];  // v0 tile, XOR chunk swizzled
  int tid = threadIdx.x, lane = tid & 63, wave = tid >> 6;
  size_t row0 = (size_t)blockIdx.x * 256;
#pragma unroll
  for (int r = 0; r < 8; ++r) {
    int row = (tid >> 3) + r * 32;
    int c8 = (tid & 7) << 3;
    const float* kp = kmat + (row0 + row) * 64 + c8;
    bf16x8 kb;
#pragma unroll
    for (int c = 0; c < 8; ++c) kb[c] = (__bf16)kp[c];
    *(bf16x8*)&kv[row][c8] = kb;
    int pc = ((tid & 7) ^ (row & 7)) << 3;
    *(bf16x8*)&v0s[row][pc] = *(const bf16x8*)&v0g[(row0 + row) * 64 + c8];
  }
  __syncthreads();
  f32x4 acc[4][4];
#pragma unroll
  for (int a = 0; a < 4; ++a)
#pragma unroll
    for (int b = 0; b < 4; ++b) acc[a][b] = f32x4{0.f, 0.f, 0.f, 0.f};
  int l15 = lane & 15, lhi = lane >> 4;
#pragma unroll 2
  for (int i = 0; i < 64; ++i) {
#pragma unroll
    for (int kk = 0; kk < 2; ++kk) {
      int kc = kk * 4 + lhi;  // logical 16B chunk within the 64-wide j range
      bf16x8 bfr[4];
#pragma unroll
      for (int nf = 0; nf < 4; ++nf)
        bfr[nf] = *(const bf16x8*)&Wvb[(size_t)((nf << 4) + l15) * 4096 + (i << 6) + (kc << 3)];
#pragma unroll
      for (int mf = 0; mf < 4; ++mf) {
        int row = wave * 64 + mf * 16 + l15;
        float kval = (float)kv[row][i];
        bf16x8 v8 = *(const bf16x8*)&v0s[row][(kc ^ (row & 7)) << 3];
        bf16x8 afr;
#pragma unroll
        for (int jj = 0; jj < 8; ++jj) afr[jj] = (__bf16)(kval * (float)v8[jj]);
#pragma unroll
        for (int nf = 0; nf < 4; ++nf)
          acc[mf][nf] = __builtin_amdgcn_mfma_f32_16x16x32_bf16(afr, bfr[nf], acc[mf][nf], 0, 0, 0);
      }
    }
  }
#pragma unroll
  for (int mf = 0; mf < 4; ++mf)
#pragma unroll
    for (int nf = 0; nf < 4; ++nf) {
      int e = (nf << 4) + l15;
      float bve = bv[e];
#pragma unroll
      for (int r = 0; r < 4; ++r) {
        int row = wave * 64 + mf * 16 + (lhi << 2) + r;
        vout[(row0 + row) * 64 + e] = (__bf16)(acc[mf][nf][r] + bve);
      }
    }
}

// ---------------- hierarchical segment sums: 255 segments per (b,h) ----------------
__global__ __launch_bounds__(256) void k_segments(
    const float* __restrict__ kmat, const __bf16* __restrict__ vmat,
    float* __restrict__ Kseg, float* __restrict__ Vseg) {
  __shared__ float Ls[255][64];
  int bh = blockIdx.x, tid = threadIdx.x;
  size_t bh2048 = (size_t)bh * 2048;
  // ---- K ----
  for (int task = tid; task < 8192; task += 256) {
    int seg = task >> 6, d = task & 63;
    const float* p = kmat + (bh2048 + seg * 16) * 64 + d;
    float s = 0.f;
#pragma unroll
    for (int u = 0; u < 16; ++u) s += p[u * 64];
    Ls[seg][d] = s;
  }
  __syncthreads();
  {
    int bprev = 0, bcur = 128, cnt = 64;
    for (int lev = 1; lev < 8; ++lev) {
      for (int task = tid; task < cnt * 64; task += 256) {
        int i = task >> 6, d = task & 63;
        Ls[bcur + i][d] = Ls[bprev + 2 * i][d] + Ls[bprev + 2 * i + 1][d];
      }
      __syncthreads();
      bprev = bcur; bcur += cnt; cnt >>= 1;
    }
  }
  for (int task = tid; task < 16320; task += 256)
    Kseg[(size_t)bh * 16320 + task] = (&Ls[0][0])[task];
  __syncthreads();
  // ---- V ----
  for (int task = tid; task < 8192; task += 256) {
    int seg = task >> 6, d = task & 63;
    const __bf16* p = vmat + (bh2048 + seg * 16) * 64 + d;
    float s = 0.f;
#pragma unroll
    for (int u = 0; u < 16; ++u) s += (float)p[u * 64];
    Ls[seg][d] = s;
  }
  __syncthreads();
  {
    int bprev = 0, bcur = 128, cnt = 64;
    for (int lev = 1; lev < 8; ++lev) {
      for (int task = tid; task < cnt * 64; task += 256) {
        int i = task >> 6, d = task & 63;
        Ls[bcur + i][d] = Ls[bprev + 2 * i][d] + Ls[bprev + 2 * i + 1][d];
      }
      __syncthreads();
      bprev = bcur; bcur += cnt; cnt >>= 1;
    }
  }
  for (int task = tid; task < 16320; task += 256)
    Vseg[(size_t)bh * 16320 + task] = (&Ls[0][0])[task];
}

// ---------------- fused attention over segments + tail, fp32 ----------------
// Block: (b,h) x 64-token tile, 512 threads (8 waves, 8 tokens per wave).
__global__ __launch_bounds__(512) void k_attn(
    const float* __restrict__ qmat, const float* __restrict__ kmat,
    const __bf16* __restrict__ vmat,
    const float* __restrict__ Kseg, const float* __restrict__ Vseg,
    __bf16* __restrict__ outp) {
  __shared__ float KsF[255 * 64];        // f32, 16B-chunk XOR swizzled
  __shared__ __bf16 Vst[64][264];        // transposed [d][s]
  __shared__ float qs[64][64];
  __shared__ __bf16 tKb[64][64];         // tail K prefix (within 16-block)
  __shared__ __bf16 tVb[64][64];         // tail V prefix
  __shared__ float attb[8][256];
  __shared__ int ridx[256];
  int tid = threadIdx.x, lane = tid & 63, wave = tid >> 6;
  int bh = blockIdx.y;
  int t0 = blockIdx.x * 64;
  size_t bh2048 = (size_t)bh * 2048;
  if (tid < 256) {
    int s = tid < 255 ? tid : 254;
    int bse = 0, c = 128, lev = 0;
    while (s >= bse + c) { bse += c; c >>= 1; ++lev; }
    ridx[tid] = (s - bse + 1) * (16 << lev) - 1;
  }
  for (int task = tid; task < 16320; task += 512) {
    int s = task >> 6, d = task & 63;
    KsF[s * 64 + ((((d >> 2) ^ (s & 7)) << 2) | (d & 3))] = Kseg[(size_t)bh * 16320 + task];
    Vst[d][s] = (__bf16)Vseg[(size_t)bh * 16320 + task];
  }
  if (tid < 64) Vst[tid][255] = (__bf16)0.f;
  for (int task = tid; task < 4096; task += 512)
    qs[task >> 6][task & 63] = qmat[(bh2048 + t0) * 64 + task];
  {  // tail prefixes; 16-token blocks are independent
    int base = (wave & 3) * 16;
    if (wave < 4) {
      float acc = 0.f;
      for (int tt = base; tt < base + 16; ++tt) {
        acc += kmat[(bh2048 + t0 + tt) * 64 + lane];
        tKb[tt][lane] = (__bf16)acc;
      }
    } else {
      float acc = 0.f;
      for (int tt = base; tt < base + 16; ++tt) {
        acc += (float)vmat[(bh2048 + t0 + tt) * 64 + lane];
        tVb[tt][lane] = (__bf16)acc;
      }
    }
  }
  __syncthreads();
  const float scale = 0.125f;
  int s0 = lane, s1 = lane + 64, s2 = lane + 128;
  int s3 = lane + 192 < 255 ? lane + 192 : 254;
  int x0 = s0 * 64, x1 = s1 * 64, x2 = s2 * 64, x3 = s3 * 64;
  int k0x = s0 & 7, k1x = s1 & 7, k2x = s2 & 7, k3x = s3 & 7;
  for (int it = 0; it < 8; ++it) {
    int tt = wave + it * 8;
    int tg = t0 + tt;
    // tail logit (lanes = d)
    float pt = qs[tt][lane] * (float)tKb[tt][lane];
#pragma unroll
    for (int off = 32; off; off >>= 1) pt += __shfl_xor(pt, off);
    float tlog = pt * scale;
    // segment dots (lanes = s, 4 segments per lane)
    f32x4 dv0 = {0, 0, 0, 0}, dv1 = {0, 0, 0, 0}, dv2 = {0, 0, 0, 0}, dv3 = {0, 0, 0, 0};
#pragma unroll 4
    for (int d4 = 0; d4 < 16; ++d4) {
      f32x4 qv = *(const f32x4*)&qs[tt][d4 << 2];
      dv0 += qv * *(const f32x4*)&KsF[x0 + ((d4 ^ k0x) << 2)];
      dv1 += qv * *(const f32x4*)&KsF[x1 + ((d4 ^ k1x) << 2)];
      dv2 += qv * *(const f32x4*)&KsF[x2 + ((d4 ^ k2x) << 2)];
      dv3 += qv * *(const f32x4*)&KsF[x3 + ((d4 ^ k3x) << 2)];
    }
    float dots[4] = {hsum4(dv0), hsum4(dv1), hsum4(dv2), hsum4(dv3)};
    float lg[4];
    bool vld[4];
#pragma unroll
    for (int j = 0; j < 4; ++j) {
      int s = lane + (j << 6);
      int sc = j < 3 ? s : s3;
      bool vv = (s < 255) && (tg >= ridx[sc]);
      vld[j] = vv;
      lg[j] = vv ? dots[j] * scale : -__builtin_inff();
    }
    float mx = fmaxf(fmaxf(lg[0], lg[1]), fmaxf(lg[2], lg[3]));
#pragma unroll
    for (int off = 32; off; off >>= 1) mx = fmaxf(mx, __shfl_xor(mx, off));
    mx = fmaxf(mx, tlog);
    float e0 = vld[0] ? __expf(lg[0] - mx) : 0.f;
    float e1 = vld[1] ? __expf(lg[1] - mx) : 0.f;
    float e2 = vld[2] ? __expf(lg[2] - mx) : 0.f;
    float e3 = vld[3] ? __expf(lg[3] - mx) : 0.f;
    float sm = e0 + e1 + e2 + e3;
#pragma unroll
    for (int off = 32; off; off >>= 1) sm += __shfl_xor(sm, off);
    float etail = __expf(tlog - mx);
    float inv = 1.f / (sm + etail);
    attb[wave][lane] = e0 * inv;
    attb[wave][lane + 64] = e1 * inv;
    attb[wave][lane + 128] = e2 * inv;
    attb[wave][lane + 192] = e3 * inv;
    float atail = etail * inv;
    __syncthreads();
    // AV (lanes = d)
    float o = atail * (float)tVb[tt][lane];
#pragma unroll 4
    for (int s8 = 0; s8 < 32; ++s8) {
      f32x4 a0 = *(const f32x4*)&attb[wave][s8 * 8];
      f32x4 a1 = *(const f32x4*)&attb[wave][s8 * 8 + 4];
      bf16x8 v8 = *(const bf16x8*)&Vst[lane][s8 * 8];
      o += a0[0] * (float)v8[0] + a0[1] * (float)v8[1] + a0[2] * (float)v8[2] + a0[3] * (float)v8[3]
         + a1[0] * (float)v8[4] + a1[1] * (float)v8[5] + a1[2] * (float)v8[6] + a1[3] * (float)v8[7];
    }
    size_t b = bh / 12, h = bh % 12;
    outp[(b * 2048 + (size_t)tg) * 768 + h * 64 + lane] = (__bf16)o;
    __syncthreads();
  }
}

// ---------------- proj GEMM: d_out = out_pre @ Wproj^T (plain bf16) ----------------
__global__ __launch_bounds__(256, 2) void k_gemm_proj(
    const __bf16* __restrict__ A, const __bf16* __restrict__ Bw,
    float* __restrict__ C) {
  __shared__ __bf16 sA[128][64], sB[128][64];
  const int K = 768;
  int tid = threadIdx.x, lane = tid & 63, wave = tid >> 6;
  int wr = wave >> 1, wc = wave & 1;
  int n0 = blockIdx.x * 128, m0 = blockIdx.y * 128;
  f32x4 acc[4][4];
#pragma unroll
  for (int a = 0; a < 4; ++a)
#pragma unroll
    for (int b = 0; b < 4; ++b) acc[a][b] = f32x4{0.f, 0.f, 0.f, 0.f};
  int srow = tid >> 3, schunk = tid & 7;
  for (int k0 = 0; k0 < K; k0 += 64) {
    __syncthreads();
#pragma unroll
    for (int r = 0; r < 4; ++r) {
      int row = srow + r * 32;
      int dst = (schunk ^ (row & 7)) << 3;
      *(bf16x8*)&sA[row][dst] = *(const bf16x8*)&A[(size_t)(m0 + row) * K + k0 + (schunk << 3)];
      *(bf16x8*)&sB[row][dst] = *(const bf16x8*)&Bw[(size_t)(n0 + row) * K + k0 + (schunk << 3)];
    }
    __syncthreads();
#pragma unroll
    for (int kk = 0; kk < 2; ++kk) {
      int kc = kk * 4 + (lane >> 4);
      bf16x8 af[4], bfv[4];
#pragma unroll
      for (int mf = 0; mf < 4; ++mf) {
        int row = wr * 64 + mf * 16 + (lane & 15);
        af[mf] = *(const bf16x8*)&sA[row][(kc ^ (row & 7)) << 3];
      }
#pragma unroll
      for (int nf = 0; nf < 4; ++nf) {
        int row = wc * 64 + nf * 16 + (lane & 15);
        bfv[nf] = *(const bf16x8*)&sB[row][(kc ^ (row & 7)) << 3];
      }
#pragma unroll
      for (int mf = 0; mf < 4; ++mf)
#pragma unroll
        for (int nf = 0; nf < 4; ++nf)
          acc[mf][nf] = __builtin_amdgcn_mfma_f32_16x16x32_bf16(af[mf], bfv[nf], acc[mf][nf], 0, 0, 0);
    }
  }
#pragma unroll
  for (int mf = 0; mf < 4; ++mf)
#pragma unroll
    for (int nf = 0; nf < 4; ++nf)
#pragma unroll
      for (int r = 0; r < 4; ++r) {
        int m = m0 + wr * 64 + mf * 16 + ((lane >> 4) << 2) + r;
        int n = n0 + wc * 64 + nf * 16 + (lane & 15);
        C[(size_t)m * 768 + n] = acc[mf][nf][r];
      }
}

// ---------------- host launch ----------------
extern "C" void kernel_launch(void* const* d_in, const int* in_sizes, int n_in,
                              void* d_out, int out_size, void* d_ws, size_t ws_size,
                              hipStream_t stream) {
  const float* x = (const float*)d_in[0];
  const float* Wqkv = (const float*)d_in[1];
  const float* Wproj = (const float*)d_in[2];
  const float* Wv = (const float*)d_in[3];
  const float* bv = (const float*)d_in[4];
  float* out = (float*)d_out;
  char* ws = (char*)d_ws;
  size_t off = 0;
  auto alloc = [&](size_t bytes) -> void* {
    void* p = (void*)(ws + off);
    off += (bytes + 255) & ~(size_t)255;
    return p;
  };
  __bf16* xh  = (__bf16*)alloc(12582912ull * 2);
  __bf16* xl  = (__bf16*)alloc(12582912ull * 2);
  __bf16* wqh = (__bf16*)alloc(1769472ull * 2);
  __bf16* wql = (__bf16*)alloc(1769472ull * 2);
  __bf16* wvb = (__bf16*)alloc(262144ull * 2);
  __bf16* wpb = (__bf16*)alloc(589824ull * 2);
  float*  qm  = (float*)alloc(12582912ull * 4);
  float*  km  = (float*)alloc(12582912ull * 4);
  __bf16* v0m = (__bf16*)alloc(12582912ull * 2);
  __bf16* vm  = (__bf16*)alloc(12582912ull * 2);
  float*  Ksg = (float*)alloc(96ull * 16320 * 4);
  float*  Vsg = (float*)alloc(96ull * 16320 * 4);
  __bf16* outp = (__bf16*)alloc(12582912ull * 2);

  k_split<<<dim3(12288), dim3(256), 0, stream>>>(x, xh, xl, 3145728);
  k_split<<<dim3(1728), dim3(256), 0, stream>>>(Wqkv, wqh, wql, 442368);
  k_cast<<<dim3(256), dim3(256), 0, stream>>>(Wv, wvb, 65536);
  k_cast<<<dim3(576), dim3(256), 0, stream>>>(Wproj, wpb, 147456);
  k_gemm_qkv<<<dim3(18, 128), dim3(256), 0, stream>>>(xh, xl, wqh, wql, qm, km, v0m);
  k_veins<<<dim3(768), dim3(256), 0, stream>>>(km, v0m, wvb, bv, vm);
  k_segments<<<dim3(96), dim3(256), 0, stream>>>(km, vm, Ksg, Vsg);
  k_attn<<<dim3(32, 96), dim3(512), 0, stream>>>(qm, km, vm, Ksg, Vsg, outp);
  k_gemm_proj<<<dim3(6, 128), dim3(256), 0, stream>>>(outp, wpb, out);
}

// Round 2
// 645.279 us; speedup vs baseline: 1.7430x; 1.7430x over previous
//
#include <hip/hip_runtime.h>

// FixSetLinearAttention: B=8 T=2048 C=768 NH=12 hs=64 Lmin=16, 255 segments + tail.
// R2: attention moved to MFMA (split-bf16 QK, bf16 PV), tail folded into MFMA as
// diagonal fragments, causal segment skipping, no barriers in k_attn2.

typedef __bf16 bf16x8 __attribute__((ext_vector_type(8)));
typedef __bf16 bf16x4 __attribute__((ext_vector_type(4)));
typedef float  f32x4  __attribute__((ext_vector_type(4)));

#define DEV __device__ __forceinline__
#define MFMA(a, b, c) __builtin_amdgcn_mfma_f32_16x16x32_bf16((a), (b), (c), 0, 0, 0)

// ---------------- prep: f32 -> bf16 (hi) + residual (lo) ----------------
__global__ __launch_bounds__(256) void k_split(const float* __restrict__ in,
                                               __bf16* __restrict__ hi,
                                               __bf16* __restrict__ lo, int n4) {
  int i = blockIdx.x * 256 + threadIdx.x;
  if (i >= n4) return;
  f32x4 x = ((const f32x4*)in)[i];
  bf16x4 h, l;
#pragma unroll
  for (int c = 0; c < 4; ++c) {
    __bf16 hh = (__bf16)x[c];
    h[c] = hh;
    l[c] = (__bf16)(x[c] - (float)hh);
  }
  ((bf16x4*)hi)[i] = h;
  ((bf16x4*)lo)[i] = l;
}

__global__ __launch_bounds__(256) void k_cast(const float* __restrict__ in,
                                              __bf16* __restrict__ outb, int n4) {
  int i = blockIdx.x * 256 + threadIdx.x;
  if (i >= n4) return;
  f32x4 v = ((const f32x4*)in)[i];
  bf16x4 o;
#pragma unroll
  for (int c = 0; c < 4; ++c) o[c] = (__bf16)v[c];
  ((bf16x4*)outb)[i] = o;
}

// ---------------- qkv GEMM: C = A @ B^T, split-bf16 (hh + hl + lh) ----------------
__global__ __launch_bounds__(256, 2) void k_gemm_qkv(
    const __bf16* __restrict__ Ah, const __bf16* __restrict__ Al,
    const __bf16* __restrict__ Bh, const __bf16* __restrict__ Bl,
    __bf16* __restrict__ qoh, __bf16* __restrict__ qol,
    float* __restrict__ ko, __bf16* __restrict__ v0o) {
  __shared__ __bf16 sAh[128][64], sAl[128][64], sBh[128][64], sBl[128][64];
  const int K = 768;
  int tid = threadIdx.x, lane = tid & 63, wave = tid >> 6;
  int wr = wave >> 1, wc = wave & 1;
  int n0 = blockIdx.x * 128, m0 = blockIdx.y * 128;
  f32x4 acc[4][4];
#pragma unroll
  for (int a = 0; a < 4; ++a)
#pragma unroll
    for (int b = 0; b < 4; ++b) acc[a][b] = f32x4{0.f, 0.f, 0.f, 0.f};
  int srow = tid >> 3, schunk = tid & 7;
  for (int k0 = 0; k0 < K; k0 += 64) {
    __syncthreads();
#pragma unroll
    for (int r = 0; r < 4; ++r) {
      int row = srow + r * 32;
      int dst = (schunk ^ (row & 7)) << 3;
      size_t asrc = (size_t)(m0 + row) * K + k0 + (schunk << 3);
      size_t bsrc = (size_t)(n0 + row) * K + k0 + (schunk << 3);
      *(bf16x8*)&sAh[row][dst] = *(const bf16x8*)&Ah[asrc];
      *(bf16x8*)&sAl[row][dst] = *(const bf16x8*)&Al[asrc];
      *(bf16x8*)&sBh[row][dst] = *(const bf16x8*)&Bh[bsrc];
      *(bf16x8*)&sBl[row][dst] = *(const bf16x8*)&Bl[bsrc];
    }
    __syncthreads();
#pragma unroll
    for (int kk = 0; kk < 2; ++kk) {
      int kc = kk * 4 + (lane >> 4);
      bf16x8 ah[4], al[4], bh[4], bl[4];
#pragma unroll
      for (int mf = 0; mf < 4; ++mf) {
        int row = wr * 64 + mf * 16 + (lane & 15);
        int cc = (kc ^ (row & 7)) << 3;
        ah[mf] = *(const bf16x8*)&sAh[row][cc];
        al[mf] = *(const bf16x8*)&sAl[row][cc];
      }
#pragma unroll
      for (int nf = 0; nf < 4; ++nf) {
        int row = wc * 64 + nf * 16 + (lane & 15);
        int cc = (kc ^ (row & 7)) << 3;
        bh[nf] = *(const bf16x8*)&sBh[row][cc];
        bl[nf] = *(const bf16x8*)&sBl[row][cc];
      }
#pragma unroll
      for (int mf = 0; mf < 4; ++mf)
#pragma unroll
        for (int nf = 0; nf < 4; ++nf) {
          acc[mf][nf] = MFMA(ah[mf], bh[nf], acc[mf][nf]);
          acc[mf][nf] = MFMA(ah[mf], bl[nf], acc[mf][nf]);
          acc[mf][nf] = MFMA(al[mf], bh[nf], acc[mf][nf]);
        }
    }
  }
  int sec = n0 / 768;
  int nb = n0 - sec * 768;
#pragma unroll
  for (int mf = 0; mf < 4; ++mf)
#pragma unroll
    for (int nf = 0; nf < 4; ++nf)
#pragma unroll
      for (int r = 0; r < 4; ++r) {
        int m = m0 + wr * 64 + mf * 16 + ((lane >> 4) << 2) + r;
        int n = nb + wc * 64 + nf * 16 + (lane & 15);
        int b = m >> 11, t = m & 2047;
        int h = n >> 6, d = n & 63;
        size_t idx = (((size_t)b * 12 + h) * 2048 + t) * 64 + d;
        float val = acc[mf][nf][r];
        if (sec == 0) {
          __bf16 hh = (__bf16)val;
          qoh[idx] = hh;
          qol[idx] = (__bf16)(val - (float)hh);
        } else if (sec == 1) {
          ko[idx] = val;
        } else {
          v0o[idx] = (__bf16)val;
        }
      }
}

// ---------------- v = (k (x) v0) @ Wv^T + bv ----------------
__global__ __launch_bounds__(256, 2) void k_veins(
    const float* __restrict__ kmat, const __bf16* __restrict__ v0g,
    const __bf16* __restrict__ Wvb, const float* __restrict__ bv,
    __bf16* __restrict__ vout) {
  __shared__ __bf16 kv[256][72];
  __shared__ __bf16 v0s[256][64];
  int tid = threadIdx.x, lane = tid & 63, wave = tid >> 6;
  size_t row0 = (size_t)blockIdx.x * 256;
#pragma unroll
  for (int r = 0; r < 8; ++r) {
    int row = (tid >> 3) + r * 32;
    int c8 = (tid & 7) << 3;
    const float* kp = kmat + (row0 + row) * 64 + c8;
    bf16x8 kb;
#pragma unroll
    for (int c = 0; c < 8; ++c) kb[c] = (__bf16)kp[c];
    *(bf16x8*)&kv[row][c8] = kb;
    int pc = ((tid & 7) ^ (row & 7)) << 3;
    *(bf16x8*)&v0s[row][pc] = *(const bf16x8*)&v0g[(row0 + row) * 64 + c8];
  }
  __syncthreads();
  f32x4 acc[4][4];
#pragma unroll
  for (int a = 0; a < 4; ++a)
#pragma unroll
    for (int b = 0; b < 4; ++b) acc[a][b] = f32x4{0.f, 0.f, 0.f, 0.f};
  int l15 = lane & 15, lhi = lane >> 4;
#pragma unroll 2
  for (int i = 0; i < 64; ++i) {
#pragma unroll
    for (int kk = 0; kk < 2; ++kk) {
      int kc = kk * 4 + lhi;
      bf16x8 bfr[4];
#pragma unroll
      for (int nf = 0; nf < 4; ++nf)
        bfr[nf] = *(const bf16x8*)&Wvb[(size_t)((nf << 4) + l15) * 4096 + (i << 6) + (kc << 3)];
#pragma unroll
      for (int mf = 0; mf < 4; ++mf) {
        int row = wave * 64 + mf * 16 + l15;
        float kval = (float)kv[row][i];
        bf16x8 v8 = *(const bf16x8*)&v0s[row][(kc ^ (row & 7)) << 3];
        bf16x8 afr;
#pragma unroll
        for (int jj = 0; jj < 8; ++jj) afr[jj] = (__bf16)(kval * (float)v8[jj]);
#pragma unroll
        for (int nf = 0; nf < 4; ++nf)
          acc[mf][nf] = MFMA(afr, bfr[nf], acc[mf][nf]);
      }
    }
  }
#pragma unroll
  for (int mf = 0; mf < 4; ++mf)
#pragma unroll
    for (int nf = 0; nf < 4; ++nf) {
      int e = (nf << 4) + l15;
      float bve = bv[e];
#pragma unroll
      for (int r = 0; r < 4; ++r) {
        int row = wave * 64 + mf * 16 + (lhi << 2) + r;
        vout[(row0 + row) * 64 + e] = (__bf16)(acc[mf][nf][r] + bve);
      }
    }
}

// ---------------- segment sums -> Kseg hi/lo bf16 [bh][256][64], Vseg^T bf16 [bh][64][256] ----------------
__global__ __launch_bounds__(256) void k_segments(
    const float* __restrict__ kmat, const __bf16* __restrict__ vmat,
    __bf16* __restrict__ Ksh, __bf16* __restrict__ Ksl, __bf16* __restrict__ Vt) {
  __shared__ float Ls[255][64];
  int bh = blockIdx.x, tid = threadIdx.x;
  size_t bh2048 = (size_t)bh * 2048;
  // ---- K ----
  for (int task = tid; task < 8192; task += 256) {
    int seg = task >> 6, d = task & 63;
    const float* p = kmat + (bh2048 + seg * 16) * 64 + d;
    float s = 0.f;
#pragma unroll
    for (int u = 0; u < 16; ++u) s += p[u * 64];
    Ls[seg][d] = s;
  }
  __syncthreads();
  {
    int bprev = 0, bcur = 128, cnt = 64;
    for (int lev = 1; lev < 8; ++lev) {
      for (int task = tid; task < cnt * 64; task += 256) {
        int i = task >> 6, d = task & 63;
        Ls[bcur + i][d] = Ls[bprev + 2 * i][d] + Ls[bprev + 2 * i + 1][d];
      }
      __syncthreads();
      bprev = bcur; bcur += cnt; cnt >>= 1;
    }
  }
  for (int task = tid; task < 16384; task += 256) {
    int seg = task >> 6;
    float v = (seg < 255) ? Ls[seg][task & 63] : 0.f;
    __bf16 h = (__bf16)v;
    Ksh[(size_t)bh * 16384 + task] = h;
    Ksl[(size_t)bh * 16384 + task] = (__bf16)(v - (float)h);
  }
  __syncthreads();
  // ---- V ----
  for (int task = tid; task < 8192; task += 256) {
    int seg = task >> 6, d = task & 63;
    const __bf16* p = vmat + (bh2048 + seg * 16) * 64 + d;
    float s = 0.f;
#pragma unroll
    for (int u = 0; u < 16; ++u) s += (float)p[u * 64];
    Ls[seg][d] = s;
  }
  __syncthreads();
  {
    int bprev = 0, bcur = 128, cnt = 64;
    for (int lev = 1; lev < 8; ++lev) {
      for (int task = tid; task < cnt * 64; task += 256) {
        int i = task >> 6, d = task & 63;
        Ls[bcur + i][d] = Ls[bprev + 2 * i][d] + Ls[bprev + 2 * i + 1][d];
      }
      __syncthreads();
      bprev = bcur; bcur += cnt; cnt >>= 1;
    }
  }
  for (int task = tid; task < 16384; task += 256) {
    int d = task >> 8, seg = task & 255;
    float v = (seg < 255) ? Ls[seg][d] : 0.f;
    Vt[(size_t)bh * 16384 + task] = (__bf16)v;
  }
}

// ---------------- MFMA attention: block = (bh, 64-tok tile), 4 waves x 16 tokens ----------------
__global__ __launch_bounds__(256) void k_attn2(
    const __bf16* __restrict__ qhm, const __bf16* __restrict__ qlm,
    const float* __restrict__ km, const __bf16* __restrict__ vm,
    const __bf16* __restrict__ Ksh, const __bf16* __restrict__ Ksl,
    const __bf16* __restrict__ Vt, __bf16* __restrict__ outp) {
  __shared__ __align__(16) __bf16 P[4][16][296];
  __shared__ __align__(16) __bf16 tK[4][16][72];
  __shared__ __align__(16) __bf16 tV[4][16][72];
  int tid = threadIdx.x, lane = tid & 63, wave = tid >> 6;
  int orig = blockIdx.y * 32 + blockIdx.x;
  int wg = (orig & 7) * 384 + (orig >> 3);  // XCD-chunked swizzle (3072 = 8*384)
  int tile = wg & 31, bh = wg >> 5;
  int t0 = tile * 64, tw0 = t0 + wave * 16;
  size_t bh2048 = (size_t)bh * 2048;
  int l15 = lane & 15, g = lane >> 4, g8 = g << 3;

  // per-wave tail prefixes (lane = d)
  {
    const float* kp = km + (bh2048 + tw0) * 64 + lane;
    const __bf16* vp = vm + (bh2048 + tw0) * 64 + lane;
    float ka = 0.f, va = 0.f;
#pragma unroll
    for (int t = 0; t < 16; ++t) {
      ka += kp[t * 64];
      va += (float)vp[t * 64];
      tK[wave][t][lane] = (__bf16)ka;
      tV[wave][t][lane] = (__bf16)va;
    }
  }
  // Q fragments (A operand): row = l15 token, k chunk = g*8 (+32)
  bf16x8 qhf[2], qlf[2];
  {
    const __bf16* qp = qhm + (bh2048 + tw0 + l15) * 64 + g8;
    qhf[0] = *(const bf16x8*)qp;
    qhf[1] = *(const bf16x8*)(qp + 32);
    const __bf16* qp2 = qlm + (bh2048 + tw0 + l15) * 64 + g8;
    qlf[0] = *(const bf16x8*)qp2;
    qlf[1] = *(const bf16x8*)(qp2 + 32);
  }
  // validity: mA = valid for all 16 tokens, mE = valid only for last token (ridx == tw0+15)
  unsigned mA = 0, mE = 0;
#pragma unroll
  for (int nf = 0; nf < 16; ++nf) {
    int seg = nf * 16 + l15;
    if (seg < 255) {
      int m = 256 - seg;                 // >= 2
      int cl = 32 - __clz(m - 1);        // ceil(log2(m))
      int lev = 8 - cl;
      int rdx = (seg - (256 - (256 >> lev)) + 1) * (16 << lev) - 1;
      if (rdx < tw0) mA |= 1u << nf;
      else if (rdx == tw0 + 15) mE |= 1u << nf;
    }
  }
  unsigned mAny = mA | mE;
  unsigned pmask = 0;
#pragma unroll
  for (int ks = 0; ks < 8; ++ks)
    if (__any((int)((mAny >> (2 * ks)) & 3u))) pmask |= 1u << ks;

  // ---- QK^T (split-bf16: qh*Kh + ql*Kh + qh*Kl) ----
  f32x4 acc[17];
#pragma unroll
  for (int i = 0; i < 17; ++i) acc[i] = f32x4{0.f, 0.f, 0.f, 0.f};
  const __bf16* KhB = Ksh + (size_t)bh * 16384;
  const __bf16* KlB = Ksl + (size_t)bh * 16384;
#pragma unroll
  for (int ks = 0; ks < 8; ++ks) {
    if ((pmask >> ks) & 1) {
      const __bf16* ph = KhB + (size_t)(ks * 32 + l15) * 64 + g8;
      const __bf16* pl = KlB + (size_t)(ks * 32 + l15) * 64 + g8;
      bf16x8 h00 = *(const bf16x8*)ph;
      bf16x8 h01 = *(const bf16x8*)(ph + 32);
      bf16x8 h10 = *(const bf16x8*)(ph + 1024);
      bf16x8 h11 = *(const bf16x8*)(ph + 1056);
      bf16x8 l00 = *(const bf16x8*)pl;
      bf16x8 l01 = *(const bf16x8*)(pl + 32);
      bf16x8 l10 = *(const bf16x8*)(pl + 1024);
      bf16x8 l11 = *(const bf16x8*)(pl + 1056);
      acc[2 * ks] = MFMA(qhf[0], h00, acc[2 * ks]);
      acc[2 * ks] = MFMA(qhf[1], h01, acc[2 * ks]);
      acc[2 * ks] = MFMA(qlf[0], h00, acc[2 * ks]);
      acc[2 * ks] = MFMA(qlf[1], h01, acc[2 * ks]);
      acc[2 * ks] = MFMA(qhf[0], l00, acc[2 * ks]);
      acc[2 * ks] = MFMA(qhf[1], l01, acc[2 * ks]);
      acc[2 * ks + 1] = MFMA(qhf[0], h10, acc[2 * ks + 1]);
      acc[2 * ks + 1] = MFMA(qhf[1], h11, acc[2 * ks + 1]);
      acc[2 * ks + 1] = MFMA(qlf[0], h10, acc[2 * ks + 1]);
      acc[2 * ks + 1] = MFMA(qlf[1], h11, acc[2 * ks + 1]);
      acc[2 * ks + 1] = MFMA(qhf[0], l10, acc[2 * ks + 1]);
      acc[2 * ks + 1] = MFMA(qhf[1], l11, acc[2 * ks + 1]);
    }
  }
  // tail fragment (nf=16): B = per-token K prefix (hi only)
  {
    const __bf16* tp = &tK[wave][l15][g8];
    bf16x8 t0f = *(const bf16x8*)tp;
    bf16x8 t1f = *(const bf16x8*)(tp + 32);
    acc[16] = MFMA(qhf[0], t0f, acc[16]);
    acc[16] = MFMA(qhf[1], t1f, acc[16]);
    acc[16] = MFMA(qlf[0], t0f, acc[16]);
    acc[16] = MFMA(qlf[1], t1f, acc[16]);
  }

  // ---- softmax (rows = tokens g*4+r, cols spread over nf in-lane and l15 cross-lane) ----
  const float scale = 0.125f;
  float mx[4], sm[4], et[4];
#pragma unroll
  for (int r = 0; r < 4; ++r) {
    int tr = g * 4 + r;
    mx[r] = (l15 == tr) ? acc[16][r] * scale : -3.0e38f;
  }
#pragma unroll
  for (int nf = 0; nf < 16; ++nf) {
    bool bA = (mA >> nf) & 1, bE = (mE >> nf) & 1;
#pragma unroll
    for (int r = 0; r < 4; ++r) {
      bool u = bA || (bE && g == 3 && r == 3);
      if (u) mx[r] = fmaxf(mx[r], acc[nf][r] * scale);
    }
  }
#pragma unroll
  for (int off = 1; off < 16; off <<= 1)
#pragma unroll
    for (int r = 0; r < 4; ++r) mx[r] = fmaxf(mx[r], __shfl_xor(mx[r], off));
#pragma unroll
  for (int r = 0; r < 4; ++r) {
    int tr = g * 4 + r;
    et[r] = (l15 == tr) ? __expf(acc[16][r] * scale - mx[r]) : 0.f;
    sm[r] = et[r];
  }
#pragma unroll
  for (int ks = 0; ks < 8; ++ks) {
    if ((pmask >> ks) & 1) {
#pragma unroll
      for (int f = 0; f < 2; ++f) {
        int nf = 2 * ks + f;
        bool bA = (mA >> nf) & 1, bE = (mE >> nf) & 1;
#pragma unroll
        for (int r = 0; r < 4; ++r) {
          bool u = bA || (bE && g == 3 && r == 3);
          float e = u ? __expf(acc[nf][r] * scale - mx[r]) : 0.f;
          acc[nf][r] = e;
          sm[r] += e;
        }
      }
    }
  }
#pragma unroll
  for (int off = 1; off < 16; off <<= 1)
#pragma unroll
    for (int r = 0; r < 4; ++r) sm[r] += __shfl_xor(sm[r], off);
  float inv[4];
#pragma unroll
  for (int r = 0; r < 4; ++r) inv[r] = 1.f / sm[r];

  // ---- P writes (per-wave LDS, no barrier needed) ----
  bf16x8 zz = {};
  *(bf16x8*)&P[wave][lane >> 2][256 + (lane & 3) * 8] = zz;
#pragma unroll
  for (int nf = 0; nf < 16; ++nf)
#pragma unroll
    for (int r = 0; r < 4; ++r)
      P[wave][g * 4 + r][nf * 16 + l15] = (__bf16)(acc[nf][r] * inv[r]);
#pragma unroll
  for (int r = 0; r < 4; ++r)
    if (l15 == g * 4 + r) P[wave][l15][256 + l15] = (__bf16)(et[r] * inv[r]);

  // ---- PV ----
  f32x4 oa[4];
#pragma unroll
  for (int i = 0; i < 4; ++i) oa[i] = f32x4{0.f, 0.f, 0.f, 0.f};
  const __bf16* VB = Vt + (size_t)bh * 16384;
#pragma unroll
  for (int ks = 0; ks < 8; ++ks) {
    if ((pmask >> ks) & 1) {
      bf16x8 pa = *(const bf16x8*)&P[wave][l15][ks * 32 + g8];
#pragma unroll
      for (int n2 = 0; n2 < 4; ++n2) {
        bf16x8 vb = *(const bf16x8*)(VB + (size_t)(n2 * 16 + l15) * 256 + ks * 32 + g8);
        oa[n2] = MFMA(pa, vb, oa[n2]);
      }
    }
  }
  {  // tail k-step (diag P block x per-token V prefix)
    bf16x8 pa = *(const bf16x8*)&P[wave][l15][256 + g8];
    int jb = (g & 1) * 8;  // clamp: lanes with k>=16 multiply P==0
#pragma unroll
    for (int n2 = 0; n2 < 4; ++n2) {
      bf16x8 vt;
#pragma unroll
      for (int jj = 0; jj < 8; ++jj) vt[jj] = tV[wave][jb + jj][n2 * 16 + l15];
      oa[n2] = MFMA(pa, vt, oa[n2]);
    }
  }
  // ---- output ----
  int b = bh / 12, h = bh - b * 12;
  size_t obase = ((size_t)b * 2048 + tw0) * 768 + h * 64;
#pragma unroll
  for (int n2 = 0; n2 < 4; ++n2)
#pragma unroll
    for (int r = 0; r < 4; ++r)
      outp[obase + (size_t)(g * 4 + r) * 768 + n2 * 16 + l15] = (__bf16)oa[n2][r];
}

// ---------------- proj GEMM ----------------
__global__ __launch_bounds__(256, 2) void k_gemm_proj(
    const __bf16* __restrict__ A, const __bf16* __restrict__ Bw,
    float* __restrict__ C) {
  __shared__ __bf16 sA[128][64], sB[128][64];
  const int K = 768;
  int tid = threadIdx.x, lane = tid & 63, wave = tid >> 6;
  int wr = wave >> 1, wc = wave & 1;
  int n0 = blockIdx.x * 128, m0 = blockIdx.y * 128;
  f32x4 acc[4][4];
#pragma unroll
  for (int a = 0; a < 4; ++a)
#pragma unroll
    for (int b = 0; b < 4; ++b) acc[a][b] = f32x4{0.f, 0.f, 0.f, 0.f};
  int srow = tid >> 3, schunk = tid & 7;
  for (int k0 = 0; k0 < K; k0 += 64) {
    __syncthreads();
#pragma unroll
    for (int r = 0; r < 4; ++r) {
      int row = srow + r * 32;
      int dst = (schunk ^ (row & 7)) << 3;
      *(bf16x8*)&sA[row][dst] = *(const bf16x8*)&A[(size_t)(m0 + row) * K + k0 + (schunk << 3)];
      *(bf16x8*)&sB[row][dst] = *(const bf16x8*)&Bw[(size_t)(n0 + row) * K + k0 + (schunk << 3)];
    }
    __syncthreads();
#pragma unroll
    for (int kk = 0; kk < 2; ++kk) {
      int kc = kk * 4 + (lane >> 4);
      bf16x8 af[4], bfv[4];
#pragma unroll
      for (int mf = 0; mf < 4; ++mf) {
        int row = wr * 64 + mf * 16 + (lane & 15);
        af[mf] = *(const bf16x8*)&sA[row][(kc ^ (row & 7)) << 3];
      }
#pragma unroll
      for (int nf = 0; nf < 4; ++nf) {
        int row = wc * 64 + nf * 16 + (lane & 15);
        bfv[nf] = *(const bf16x8*)&sB[row][(kc ^ (row & 7)) << 3];
      }
#pragma unroll
      for (int mf = 0; mf < 4; ++mf)
#pragma unroll
        for (int nf = 0; nf < 4; ++nf)
          acc[mf][nf] = MFMA(af[mf], bfv[nf], acc[mf][nf]);
    }
  }
#pragma unroll
  for (int mf = 0; mf < 4; ++mf)
#pragma unroll
    for (int nf = 0; nf < 4; ++nf)
#pragma unroll
      for (int r = 0; r < 4; ++r) {
        int m = m0 + wr * 64 + mf * 16 + ((lane >> 4) << 2) + r;
        int n = n0 + wc * 64 + nf * 16 + (lane & 15);
        C[(size_t)m * 768 + n] = acc[mf][nf][r];
      }
}

// ---------------- host launch ----------------
extern "C" void kernel_launch(void* const* d_in, const int* in_sizes, int n_in,
                              void* d_out, int out_size, void* d_ws, size_t ws_size,
                              hipStream_t stream) {
  const float* x = (const float*)d_in[0];
  const float* Wqkv = (const float*)d_in[1];
  const float* Wproj = (const float*)d_in[2];
  const float* Wv = (const float*)d_in[3];
  const float* bv = (const float*)d_in[4];
  float* out = (float*)d_out;
  char* ws = (char*)d_ws;
  size_t off = 0;
  auto alloc = [&](size_t bytes) -> void* {
    void* p = (void*)(ws + off);
    off += (bytes + 255) & ~(size_t)255;
    return p;
  };
  __bf16* xh  = (__bf16*)alloc(12582912ull * 2);
  __bf16* xl  = (__bf16*)alloc(12582912ull * 2);
  __bf16* wqh = (__bf16*)alloc(1769472ull * 2);
  __bf16* wql = (__bf16*)alloc(1769472ull * 2);
  __bf16* wvb = (__bf16*)alloc(262144ull * 2);
  __bf16* wpb = (__bf16*)alloc(589824ull * 2);
  __bf16* qhm = (__bf16*)alloc(12582912ull * 2);
  __bf16* qlm = (__bf16*)alloc(12582912ull * 2);
  float*  km  = (float*)alloc(12582912ull * 4);
  __bf16* v0m = (__bf16*)alloc(12582912ull * 2);
  __bf16* vm  = (__bf16*)alloc(12582912ull * 2);
  __bf16* Ksh = (__bf16*)alloc(1572864ull * 2);
  __bf16* Ksl = (__bf16*)alloc(1572864ull * 2);
  __bf16* Vt  = (__bf16*)alloc(1572864ull * 2);
  __bf16* outp = (__bf16*)alloc(12582912ull * 2);

  k_split<<<dim3(12288), dim3(256), 0, stream>>>(x, xh, xl, 3145728);
  k_split<<<dim3(1728), dim3(256), 0, stream>>>(Wqkv, wqh, wql, 442368);
  k_cast<<<dim3(256), dim3(256), 0, stream>>>(Wv, wvb, 65536);
  k_cast<<<dim3(576), dim3(256), 0, stream>>>(Wproj, wpb, 147456);
  k_gemm_qkv<<<dim3(18, 128), dim3(256), 0, stream>>>(xh, xl, wqh, wql, qhm, qlm, km, v0m);
  k_veins<<<dim3(768), dim3(256), 0, stream>>>(km, v0m, wvb, bv, vm);
  k_segments<<<dim3(96), dim3(256), 0, stream>>>(km, vm, Ksh, Ksl, Vt);
  k_attn2<<<dim3(32, 96), dim3(256), 0, stream>>>(qhm, qlm, km, vm, Ksh, Ksl, Vt, outp);
  k_gemm_proj<<<dim3(6, 128), dim3(256), 0, stream>>>(outp, wpb, out);
}

// Round 4
// 597.775 us; speedup vs baseline: 1.8815x; 1.0795x over previous
//
#include <hip/hip_runtime.h>

// FixSetLinearAttention: B=8 T=2048 C=768 NH=12 hs=64 Lmin=16, 255 segments + tail.
// R4 = R3 fixed: workspace overflow (269.9MB > ws_size) was the crash. khm buffer
// removed (veins converts f32->fp16 during staging); outp aliased onto xh.
// Footprint ~209MB (R2's 244.7MB is known-good).

typedef __bf16 bf16x8 __attribute__((ext_vector_type(8)));
typedef __bf16 bf16x4 __attribute__((ext_vector_type(4)));
typedef float  f32x4  __attribute__((ext_vector_type(4)));
typedef _Float16 half8 __attribute__((ext_vector_type(8)));
typedef _Float16 half4 __attribute__((ext_vector_type(4)));

#define DEV __device__ __forceinline__
#define MFMA(a, b, c) __builtin_amdgcn_mfma_f32_16x16x32_bf16((a), (b), (c), 0, 0, 0)
#define MFMA16(a, b, c) __builtin_amdgcn_mfma_f32_16x16x32_f16((a), (b), (c), 0, 0, 0)

// ---------------- prep: f32 -> bf16 (hi) + residual (lo) ----------------
__global__ __launch_bounds__(256) void k_split(const float* __restrict__ in,
                                               __bf16* __restrict__ hi,
                                               __bf16* __restrict__ lo, int n4) {
  int i = blockIdx.x * 256 + threadIdx.x;
  if (i >= n4) return;
  f32x4 x = ((const f32x4*)in)[i];
  bf16x4 h, l;
#pragma unroll
  for (int c = 0; c < 4; ++c) {
    __bf16 hh = (__bf16)x[c];
    h[c] = hh;
    l[c] = (__bf16)(x[c] - (float)hh);
  }
  ((bf16x4*)hi)[i] = h;
  ((bf16x4*)lo)[i] = l;
}

__global__ __launch_bounds__(256) void k_cast(const float* __restrict__ in,
                                              __bf16* __restrict__ outb, int n4) {
  int i = blockIdx.x * 256 + threadIdx.x;
  if (i >= n4) return;
  f32x4 v = ((const f32x4*)in)[i];
  bf16x4 o;
#pragma unroll
  for (int c = 0; c < 4; ++c) o[c] = (__bf16)v[c];
  ((bf16x4*)outb)[i] = o;
}

__global__ __launch_bounds__(256) void k_cast16(const float* __restrict__ in,
                                                _Float16* __restrict__ outh, int n4) {
  int i = blockIdx.x * 256 + threadIdx.x;
  if (i >= n4) return;
  f32x4 v = ((const f32x4*)in)[i];
  half4 o;
#pragma unroll
  for (int c = 0; c < 4; ++c) o[c] = (_Float16)v[c];
  ((half4*)outh)[i] = o;
}

// ---------------- qkv GEMM: C = A @ B^T, split-bf16 (hh + hl + lh; hh-only for v0) --------
__global__ __launch_bounds__(256, 2) void k_gemm_qkv(
    const __bf16* __restrict__ Ah, const __bf16* __restrict__ Al,
    const __bf16* __restrict__ Bh, const __bf16* __restrict__ Bl,
    __bf16* __restrict__ qoh, __bf16* __restrict__ qol,
    float* __restrict__ ko, _Float16* __restrict__ v0o) {
  __shared__ __bf16 sAh[128][64], sAl[128][64], sBh[128][64], sBl[128][64];
  const int K = 768;
  int tid = threadIdx.x, lane = tid & 63, wave = tid >> 6;
  int wr = wave >> 1, wc = wave & 1;
  int n0 = blockIdx.x * 128, m0 = blockIdx.y * 128;
  int sec = n0 / 768;
  bool dolo = (sec != 2);  // v0 section is linear -> hh pass only
  f32x4 acc[4][4];
#pragma unroll
  for (int a = 0; a < 4; ++a)
#pragma unroll
    for (int b = 0; b < 4; ++b) acc[a][b] = f32x4{0.f, 0.f, 0.f, 0.f};
  int srow = tid >> 3, schunk = tid & 7;
  for (int k0 = 0; k0 < K; k0 += 64) {
    __syncthreads();
#pragma unroll
    for (int r = 0; r < 4; ++r) {
      int row = srow + r * 32;
      int dst = (schunk ^ (row & 7)) << 3;
      size_t asrc = (size_t)(m0 + row) * K + k0 + (schunk << 3);
      size_t bsrc = (size_t)(n0 + row) * K + k0 + (schunk << 3);
      *(bf16x8*)&sAh[row][dst] = *(const bf16x8*)&Ah[asrc];
      *(bf16x8*)&sBh[row][dst] = *(const bf16x8*)&Bh[bsrc];
      if (dolo) {
        *(bf16x8*)&sAl[row][dst] = *(const bf16x8*)&Al[asrc];
        *(bf16x8*)&sBl[row][dst] = *(const bf16x8*)&Bl[bsrc];
      }
    }
    __syncthreads();
#pragma unroll
    for (int kk = 0; kk < 2; ++kk) {
      int kc = kk * 4 + (lane >> 4);
      bf16x8 ah[4], al[4], bh[4], bl[4];
#pragma unroll
      for (int mf = 0; mf < 4; ++mf) {
        int row = wr * 64 + mf * 16 + (lane & 15);
        int cc = (kc ^ (row & 7)) << 3;
        ah[mf] = *(const bf16x8*)&sAh[row][cc];
        if (dolo) al[mf] = *(const bf16x8*)&sAl[row][cc];
      }
#pragma unroll
      for (int nf = 0; nf < 4; ++nf) {
        int row = wc * 64 + nf * 16 + (lane & 15);
        int cc = (kc ^ (row & 7)) << 3;
        bh[nf] = *(const bf16x8*)&sBh[row][cc];
        if (dolo) bl[nf] = *(const bf16x8*)&sBl[row][cc];
      }
#pragma unroll
      for (int mf = 0; mf < 4; ++mf)
#pragma unroll
        for (int nf = 0; nf < 4; ++nf) {
          acc[mf][nf] = MFMA(ah[mf], bh[nf], acc[mf][nf]);
          if (dolo) {
            acc[mf][nf] = MFMA(ah[mf], bl[nf], acc[mf][nf]);
            acc[mf][nf] = MFMA(al[mf], bh[nf], acc[mf][nf]);
          }
        }
    }
  }
  int nb = n0 - sec * 768;
#pragma unroll
  for (int mf = 0; mf < 4; ++mf)
#pragma unroll
    for (int nf = 0; nf < 4; ++nf)
#pragma unroll
      for (int r = 0; r < 4; ++r) {
        int m = m0 + wr * 64 + mf * 16 + ((lane >> 4) << 2) + r;
        int n = nb + wc * 64 + nf * 16 + (lane & 15);
        int b = m >> 11, t = m & 2047;
        int h = n >> 6, d = n & 63;
        size_t idx = (((size_t)b * 12 + h) * 2048 + t) * 64 + d;
        float val = acc[mf][nf][r];
        if (sec == 0) {
          __bf16 hh = (__bf16)val;
          qoh[idx] = hh;
          qol[idx] = (__bf16)(val - (float)hh);
        } else if (sec == 1) {
          ko[idx] = val;
        } else {
          v0o[idx] = (_Float16)val;
        }
      }
}

// ---------------- v = (k (x) v0) @ Wv^T + bv  (fp16, reg v0, B prefetch) ----------------
// 256 token-rows/block, 4 waves x 64 rows. K = 4096 (i outer 64, j-half kk inner 2).
__global__ __launch_bounds__(256, 3) void k_veins(
    const float* __restrict__ km, const _Float16* __restrict__ v0g,
    const _Float16* __restrict__ Wvh, const float* __restrict__ bv,
    __bf16* __restrict__ vout) {
  __shared__ _Float16 ks[256][72];  // 36 KB
  int tid = threadIdx.x, lane = tid & 63, wave = tid >> 6;
  int l15 = lane & 15, g = lane >> 4, g8 = g << 3;
  size_t row0 = (size_t)blockIdx.x * 256;
  // stage k tile: f32 -> fp16 convert during staging
#pragma unroll
  for (int r = 0; r < 8; ++r) {
    int row = (tid >> 3) + r * 32;
    int c8 = (tid & 7) << 3;
    const float* kp = km + (row0 + row) * 64 + c8;
    f32x4 k0 = *(const f32x4*)kp;
    f32x4 k1 = *(const f32x4*)(kp + 4);
    half8 kb;
#pragma unroll
    for (int c = 0; c < 4; ++c) {
      kb[c] = (_Float16)k0[c];
      kb[c + 4] = (_Float16)k1[c];
    }
    *(half8*)&ks[row][c8] = kb;
  }
  // v0 fragments resident in regs: [mf][kk]
  half8 v0r[4][2];
#pragma unroll
  for (int mf = 0; mf < 4; ++mf) {
    size_t rb = (row0 + wave * 64 + mf * 16 + l15) * 64;
#pragma unroll
    for (int kk = 0; kk < 2; ++kk)
      v0r[mf][kk] = *(const half8*)&v0g[rb + kk * 32 + g8];
  }
  f32x4 acc[4][4];
#pragma unroll
  for (int a = 0; a < 4; ++a)
#pragma unroll
    for (int b = 0; b < 4; ++b) acc[a][b] = f32x4{0.f, 0.f, 0.f, 0.f};

  const _Float16* W0 = Wvh + (size_t)l15 * 4096 + g8;
  half8 bA[4], bB[4];
#pragma unroll
  for (int nf = 0; nf < 4; ++nf) bA[nf] = *(const half8*)&W0[(size_t)nf * 16 * 4096];
  __syncthreads();
  int r0 = wave * 64 + l15;
  for (int i = 0; i < 64; ++i) {
    // prefetch j-half 1 of this i
#pragma unroll
    for (int nf = 0; nf < 4; ++nf)
      bB[nf] = *(const half8*)&W0[(size_t)nf * 16 * 4096 + i * 64 + 32];
    _Float16 kv0 = ks[r0][i];
    _Float16 kv1 = ks[r0 + 16][i];
    _Float16 kv2 = ks[r0 + 32][i];
    _Float16 kv3 = ks[r0 + 48][i];
    {
      half8 a0 = v0r[0][0] * kv0, a1 = v0r[1][0] * kv1;
      half8 a2 = v0r[2][0] * kv2, a3 = v0r[3][0] * kv3;
#pragma unroll
      for (int nf = 0; nf < 4; ++nf) {
        acc[0][nf] = MFMA16(a0, bA[nf], acc[0][nf]);
        acc[1][nf] = MFMA16(a1, bA[nf], acc[1][nf]);
        acc[2][nf] = MFMA16(a2, bA[nf], acc[2][nf]);
        acc[3][nf] = MFMA16(a3, bA[nf], acc[3][nf]);
      }
    }
    // prefetch j-half 0 of next i
    if (i < 63) {
#pragma unroll
      for (int nf = 0; nf < 4; ++nf)
        bA[nf] = *(const half8*)&W0[(size_t)nf * 16 * 4096 + (i + 1) * 64];
    }
    {
      half8 a0 = v0r[0][1] * kv0, a1 = v0r[1][1] * kv1;
      half8 a2 = v0r[2][1] * kv2, a3 = v0r[3][1] * kv3;
#pragma unroll
      for (int nf = 0; nf < 4; ++nf) {
        acc[0][nf] = MFMA16(a0, bB[nf], acc[0][nf]);
        acc[1][nf] = MFMA16(a1, bB[nf], acc[1][nf]);
        acc[2][nf] = MFMA16(a2, bB[nf], acc[2][nf]);
        acc[3][nf] = MFMA16(a3, bB[nf], acc[3][nf]);
      }
    }
  }
#pragma unroll
  for (int mf = 0; mf < 4; ++mf)
#pragma unroll
    for (int nf = 0; nf < 4; ++nf) {
      int e = (nf << 4) + l15;
      float bve = bv[e];
#pragma unroll
      for (int r = 0; r < 4; ++r) {
        int row = wave * 64 + mf * 16 + (g << 2) + r;
        vout[(row0 + row) * 64 + e] = (__bf16)(acc[mf][nf][r] + bve);
      }
    }
}

// ---------------- segment sums -> Kseg hi/lo bf16 [bh][256][64], Vseg^T bf16 [bh][64][256] ----------------
__global__ __launch_bounds__(256) void k_segments(
    const float* __restrict__ kmat, const __bf16* __restrict__ vmat,
    __bf16* __restrict__ Ksh, __bf16* __restrict__ Ksl, __bf16* __restrict__ Vt) {
  __shared__ float Ls[255][64];
  int bh = blockIdx.x, tid = threadIdx.x;
  size_t bh2048 = (size_t)bh * 2048;
  // ---- K ----
  for (int task = tid; task < 8192; task += 256) {
    int seg = task >> 6, d = task & 63;
    const float* p = kmat + (bh2048 + seg * 16) * 64 + d;
    float s = 0.f;
#pragma unroll
    for (int u = 0; u < 16; ++u) s += p[u * 64];
    Ls[seg][d] = s;
  }
  __syncthreads();
  {
    int bprev = 0, bcur = 128, cnt = 64;
    for (int lev = 1; lev < 8; ++lev) {
      for (int task = tid; task < cnt * 64; task += 256) {
        int i = task >> 6, d = task & 63;
        Ls[bcur + i][d] = Ls[bprev + 2 * i][d] + Ls[bprev + 2 * i + 1][d];
      }
      __syncthreads();
      bprev = bcur; bcur += cnt; cnt >>= 1;
    }
  }
  for (int task = tid; task < 16384; task += 256) {
    int seg = task >> 6;
    float v = (seg < 255) ? Ls[seg][task & 63] : 0.f;
    __bf16 h = (__bf16)v;
    Ksh[(size_t)bh * 16384 + task] = h;
    Ksl[(size_t)bh * 16384 + task] = (__bf16)(v - (float)h);
  }
  __syncthreads();
  // ---- V ----
  for (int task = tid; task < 8192; task += 256) {
    int seg = task >> 6, d = task & 63;
    const __bf16* p = vmat + (bh2048 + seg * 16) * 64 + d;
    float s = 0.f;
#pragma unroll
    for (int u = 0; u < 16; ++u) s += (float)p[u * 64];
    Ls[seg][d] = s;
  }
  __syncthreads();
  {
    int bprev = 0, bcur = 128, cnt = 64;
    for (int lev = 1; lev < 8; ++lev) {
      for (int task = tid; task < cnt * 64; task += 256) {
        int i = task >> 6, d = task & 63;
        Ls[bcur + i][d] = Ls[bprev + 2 * i][d] + Ls[bprev + 2 * i + 1][d];
      }
      __syncthreads();
      bprev = bcur; bcur += cnt; cnt >>= 1;
    }
  }
  for (int task = tid; task < 16384; task += 256) {
    int d = task >> 8, seg = task & 255;
    float v = (seg < 255) ? Ls[seg][d] : 0.f;
    Vt[(size_t)bh * 16384 + task] = (__bf16)v;
  }
}

// ---------------- MFMA attention: block = (bh, 64-tok tile), 4 waves x 16 tokens ----------------
__global__ __launch_bounds__(256) void k_attn2(
    const __bf16* __restrict__ qhm, const __bf16* __restrict__ qlm,
    const float* __restrict__ km, const __bf16* __restrict__ vm,
    const __bf16* __restrict__ Ksh, const __bf16* __restrict__ Ksl,
    const __bf16* __restrict__ Vt, __bf16* __restrict__ outp) {
  __shared__ __align__(16) __bf16 P[4][16][296];
  __shared__ __align__(16) __bf16 tK[4][16][72];
  __shared__ __align__(16) __bf16 tV[4][16][72];
  int tid = threadIdx.x, lane = tid & 63, wave = tid >> 6;
  int orig = blockIdx.y * 32 + blockIdx.x;
  int wg = (orig & 7) * 384 + (orig >> 3);  // XCD-chunked swizzle (3072 = 8*384)
  int tile = wg & 31, bh = wg >> 5;
  int t0 = tile * 64, tw0 = t0 + wave * 16;
  size_t bh2048 = (size_t)bh * 2048;
  int l15 = lane & 15, g = lane >> 4, g8 = g << 3;

  // per-wave tail prefixes (lane = d)
  {
    const float* kp = km + (bh2048 + tw0) * 64 + lane;
    const __bf16* vp = vm + (bh2048 + tw0) * 64 + lane;
    float ka = 0.f, va = 0.f;
#pragma unroll
    for (int t = 0; t < 16; ++t) {
      ka += kp[t * 64];
      va += (float)vp[t * 64];
      tK[wave][t][lane] = (__bf16)ka;
      tV[wave][t][lane] = (__bf16)va;
    }
  }
  // Q fragments (A operand): row = l15 token, k chunk = g*8 (+32)
  bf16x8 qhf[2], qlf[2];
  {
    const __bf16* qp = qhm + (bh2048 + tw0 + l15) * 64 + g8;
    qhf[0] = *(const bf16x8*)qp;
    qhf[1] = *(const bf16x8*)(qp + 32);
    const __bf16* qp2 = qlm + (bh2048 + tw0 + l15) * 64 + g8;
    qlf[0] = *(const bf16x8*)qp2;
    qlf[1] = *(const bf16x8*)(qp2 + 32);
  }
  // validity: mA = valid for all 16 tokens, mE = valid only for last token (ridx == tw0+15)
  unsigned mA = 0, mE = 0;
#pragma unroll
  for (int nf = 0; nf < 16; ++nf) {
    int seg = nf * 16 + l15;
    if (seg < 255) {
      int m = 256 - seg;                 // >= 2
      int cl = 32 - __clz(m - 1);        // ceil(log2(m))
      int lev = 8 - cl;
      int rdx = (seg - (256 - (256 >> lev)) + 1) * (16 << lev) - 1;
      if (rdx < tw0) mA |= 1u << nf;
      else if (rdx == tw0 + 15) mE |= 1u << nf;
    }
  }
  unsigned mAny = mA | mE;
  unsigned pmask = 0;
#pragma unroll
  for (int ks = 0; ks < 8; ++ks)
    if (__any((int)((mAny >> (2 * ks)) & 3u))) pmask |= 1u << ks;

  // ---- QK^T (split-bf16: qh*Kh + ql*Kh + qh*Kl) ----
  f32x4 acc[17];
#pragma unroll
  for (int i = 0; i < 17; ++i) acc[i] = f32x4{0.f, 0.f, 0.f, 0.f};
  const __bf16* KhB = Ksh + (size_t)bh * 16384;
  const __bf16* KlB = Ksl + (size_t)bh * 16384;
#pragma unroll
  for (int ks = 0; ks < 8; ++ks) {
    if ((pmask >> ks) & 1) {
      const __bf16* ph = KhB + (size_t)(ks * 32 + l15) * 64 + g8;
      const __bf16* pl = KlB + (size_t)(ks * 32 + l15) * 64 + g8;
      bf16x8 h00 = *(const bf16x8*)ph;
      bf16x8 h01 = *(const bf16x8*)(ph + 32);
      bf16x8 h10 = *(const bf16x8*)(ph + 1024);
      bf16x8 h11 = *(const bf16x8*)(ph + 1056);
      bf16x8 l00 = *(const bf16x8*)pl;
      bf16x8 l01 = *(const bf16x8*)(pl + 32);
      bf16x8 l10 = *(const bf16x8*)(pl + 1024);
      bf16x8 l11 = *(const bf16x8*)(pl + 1056);
      acc[2 * ks] = MFMA(qhf[0], h00, acc[2 * ks]);
      acc[2 * ks] = MFMA(qhf[1], h01, acc[2 * ks]);
      acc[2 * ks] = MFMA(qlf[0], h00, acc[2 * ks]);
      acc[2 * ks] = MFMA(qlf[1], h01, acc[2 * ks]);
      acc[2 * ks] = MFMA(qhf[0], l00, acc[2 * ks]);
      acc[2 * ks] = MFMA(qhf[1], l01, acc[2 * ks]);
      acc[2 * ks + 1] = MFMA(qhf[0], h10, acc[2 * ks + 1]);
      acc[2 * ks + 1] = MFMA(qhf[1], h11, acc[2 * ks + 1]);
      acc[2 * ks + 1] = MFMA(qlf[0], h10, acc[2 * ks + 1]);
      acc[2 * ks + 1] = MFMA(qlf[1], h11, acc[2 * ks + 1]);
      acc[2 * ks + 1] = MFMA(qhf[0], l10, acc[2 * ks + 1]);
      acc[2 * ks + 1] = MFMA(qhf[1], l11, acc[2 * ks + 1]);
    }
  }
  // tail fragment (nf=16): B = per-token K prefix (hi only)
  {
    const __bf16* tp = &tK[wave][l15][g8];
    bf16x8 t0f = *(const bf16x8*)tp;
    bf16x8 t1f = *(const bf16x8*)(tp + 32);
    acc[16] = MFMA(qhf[0], t0f, acc[16]);
    acc[16] = MFMA(qhf[1], t1f, acc[16]);
    acc[16] = MFMA(qlf[0], t0f, acc[16]);
    acc[16] = MFMA(qlf[1], t1f, acc[16]);
  }

  // ---- softmax ----
  const float scale = 0.125f;
  float mx[4], sm[4], et[4];
#pragma unroll
  for (int r = 0; r < 4; ++r) {
    int tr = g * 4 + r;
    mx[r] = (l15 == tr) ? acc[16][r] * scale : -3.0e38f;
  }
#pragma unroll
  for (int nf = 0; nf < 16; ++nf) {
    bool bA = (mA >> nf) & 1, bE = (mE >> nf) & 1;
#pragma unroll
    for (int r = 0; r < 4; ++r) {
      bool u = bA || (bE && g == 3 && r == 3);
      if (u) mx[r] = fmaxf(mx[r], acc[nf][r] * scale);
    }
  }
#pragma unroll
  for (int off = 1; off < 16; off <<= 1)
#pragma unroll
    for (int r = 0; r < 4; ++r) mx[r] = fmaxf(mx[r], __shfl_xor(mx[r], off));
#pragma unroll
  for (int r = 0; r < 4; ++r) {
    int tr = g * 4 + r;
    et[r] = (l15 == tr) ? __expf(acc[16][r] * scale - mx[r]) : 0.f;
    sm[r] = et[r];
  }
#pragma unroll
  for (int ks = 0; ks < 8; ++ks) {
    if ((pmask >> ks) & 1) {
#pragma unroll
      for (int f = 0; f < 2; ++f) {
        int nf = 2 * ks + f;
        bool bA = (mA >> nf) & 1, bE = (mE >> nf) & 1;
#pragma unroll
        for (int r = 0; r < 4; ++r) {
          bool u = bA || (bE && g == 3 && r == 3);
          float e = u ? __expf(acc[nf][r] * scale - mx[r]) : 0.f;
          acc[nf][r] = e;
          sm[r] += e;
        }
      }
    }
  }
#pragma unroll
  for (int off = 1; off < 16; off <<= 1)
#pragma unroll
    for (int r = 0; r < 4; ++r) sm[r] += __shfl_xor(sm[r], off);
  float inv[4];
#pragma unroll
  for (int r = 0; r < 4; ++r) inv[r] = 1.f / sm[r];

  // ---- P writes (per-wave LDS, no barrier needed) ----
  bf16x8 zz = {};
  *(bf16x8*)&P[wave][lane >> 2][256 + (lane & 3) * 8] = zz;
#pragma unroll
  for (int nf = 0; nf < 16; ++nf)
#pragma unroll
    for (int r = 0; r < 4; ++r)
      P[wave][g * 4 + r][nf * 16 + l15] = (__bf16)(acc[nf][r] * inv[r]);
#pragma unroll
  for (int r = 0; r < 4; ++r)
    if (l15 == g * 4 + r) P[wave][l15][256 + l15] = (__bf16)(et[r] * inv[r]);

  // ---- PV ----
  f32x4 oa[4];
#pragma unroll
  for (int i = 0; i < 4; ++i) oa[i] = f32x4{0.f, 0.f, 0.f, 0.f};
  const __bf16* VB = Vt + (size_t)bh * 16384;
#pragma unroll
  for (int ks = 0; ks < 8; ++ks) {
    if ((pmask >> ks) & 1) {
      bf16x8 pa = *(const bf16x8*)&P[wave][l15][ks * 32 + g8];
#pragma unroll
      for (int n2 = 0; n2 < 4; ++n2) {
        bf16x8 vb = *(const bf16x8*)(VB + (size_t)(n2 * 16 + l15) * 256 + ks * 32 + g8);
        oa[n2] = MFMA(pa, vb, oa[n2]);
      }
    }
  }
  {  // tail k-step (diag P block x per-token V prefix)
    bf16x8 pa = *(const bf16x8*)&P[wave][l15][256 + g8];
    int jb = (g & 1) * 8;
#pragma unroll
    for (int n2 = 0; n2 < 4; ++n2) {
      bf16x8 vt;
#pragma unroll
      for (int jj = 0; jj < 8; ++jj) vt[jj] = tV[wave][jb + jj][n2 * 16 + l15];
      oa[n2] = MFMA(pa, vt, oa[n2]);
    }
  }
  // ---- output ----
  int b = bh / 12, h = bh - b * 12;
  size_t obase = ((size_t)b * 2048 + tw0) * 768 + h * 64;
#pragma unroll
  for (int n2 = 0; n2 < 4; ++n2)
#pragma unroll
    for (int r = 0; r < 4; ++r)
      outp[obase + (size_t)(g * 4 + r) * 768 + n2 * 16 + l15] = (__bf16)oa[n2][r];
}

// ---------------- proj GEMM ----------------
__global__ __launch_bounds__(256, 2) void k_gemm_proj(
    const __bf16* __restrict__ A, const __bf16* __restrict__ Bw,
    float* __restrict__ C) {
  __shared__ __bf16 sA[128][64], sB[128][64];
  const int K = 768;
  int tid = threadIdx.x, lane = tid & 63, wave = tid >> 6;
  int wr = wave >> 1, wc = wave & 1;
  int n0 = blockIdx.x * 128, m0 = blockIdx.y * 128;
  f32x4 acc[4][4];
#pragma unroll
  for (int a = 0; a < 4; ++a)
#pragma unroll
    for (int b = 0; b < 4; ++b) acc[a][b] = f32x4{0.f, 0.f, 0.f, 0.f};
  int srow = tid >> 3, schunk = tid & 7;
  for (int k0 = 0; k0 < K; k0 += 64) {
    __syncthreads();
#pragma unroll
    for (int r = 0; r < 4; ++r) {
      int row = srow + r * 32;
      int dst = (schunk ^ (row & 7)) << 3;
      *(bf16x8*)&sA[row][dst] = *(const bf16x8*)&A[(size_t)(m0 + row) * K + k0 + (schunk << 3)];
      *(bf16x8*)&sB[row][dst] = *(const bf16x8*)&Bw[(size_t)(n0 + row) * K + k0 + (schunk << 3)];
    }
    __syncthreads();
#pragma unroll
    for (int kk = 0; kk < 2; ++kk) {
      int kc = kk * 4 + (lane >> 4);
      bf16x8 af[4], bfv[4];
#pragma unroll
      for (int mf = 0; mf < 4; ++mf) {
        int row = wr * 64 + mf * 16 + (lane & 15);
        af[mf] = *(const bf16x8*)&sA[row][(kc ^ (row & 7)) << 3];
      }
#pragma unroll
      for (int nf = 0; nf < 4; ++nf) {
        int row = wc * 64 + nf * 16 + (lane & 15);
        bfv[nf] = *(const bf16x8*)&sB[row][(kc ^ (row & 7)) << 3];
      }
#pragma unroll
      for (int mf = 0; mf < 4; ++mf)
#pragma unroll
        for (int nf = 0; nf < 4; ++nf)
          acc[mf][nf] = MFMA(af[mf], bfv[nf], acc[mf][nf]);
    }
  }
#pragma unroll
  for (int mf = 0; mf < 4; ++mf)
#pragma unroll
    for (int nf = 0; nf < 4; ++nf)
#pragma unroll
      for (int r = 0; r < 4; ++r) {
        int m = m0 + wr * 64 + mf * 16 + ((lane >> 4) << 2) + r;
        int n = n0 + wc * 64 + nf * 16 + (lane & 15);
        C[(size_t)m * 768 + n] = acc[mf][nf][r];
      }
}

// ---------------- host launch ----------------
extern "C" void kernel_launch(void* const* d_in, const int* in_sizes, int n_in,
                              void* d_out, int out_size, void* d_ws, size_t ws_size,
                              hipStream_t stream) {
  const float* x = (const float*)d_in[0];
  const float* Wqkv = (const float*)d_in[1];
  const float* Wproj = (const float*)d_in[2];
  const float* Wv = (const float*)d_in[3];
  const float* bv = (const float*)d_in[4];
  float* out = (float*)d_out;
  char* ws = (char*)d_ws;
  size_t off = 0;
  auto alloc = [&](size_t bytes) -> void* {
    void* p = (void*)(ws + off);
    off += (bytes + 255) & ~(size_t)255;
    return p;
  };
  __bf16* xh  = (__bf16*)alloc(12582912ull * 2);   // aliased: outp reuses this after gemm_qkv
  __bf16* xl  = (__bf16*)alloc(12582912ull * 2);
  __bf16* wqh = (__bf16*)alloc(1769472ull * 2);
  __bf16* wql = (__bf16*)alloc(1769472ull * 2);
  _Float16* wvh = (_Float16*)alloc(262144ull * 2);
  __bf16* wpb = (__bf16*)alloc(589824ull * 2);
  __bf16* qhm = (__bf16*)alloc(12582912ull * 2);
  __bf16* qlm = (__bf16*)alloc(12582912ull * 2);
  float*  km  = (float*)alloc(12582912ull * 4);
  _Float16* v0m = (_Float16*)alloc(12582912ull * 2);
  __bf16* vm  = (__bf16*)alloc(12582912ull * 2);
  __bf16* Ksh = (__bf16*)alloc(1572864ull * 2);
  __bf16* Ksl = (__bf16*)alloc(1572864ull * 2);
  __bf16* Vt  = (__bf16*)alloc(1572864ull * 2);
  __bf16* outp = xh;  // alias: xh dead after k_gemm_qkv, outp born at k_attn2

  k_split<<<dim3(12288), dim3(256), 0, stream>>>(x, xh, xl, 3145728);
  k_split<<<dim3(1728), dim3(256), 0, stream>>>(Wqkv, wqh, wql, 442368);
  k_cast16<<<dim3(256), dim3(256), 0, stream>>>(Wv, wvh, 65536);
  k_cast<<<dim3(576), dim3(256), 0, stream>>>(Wproj, wpb, 147456);
  k_gemm_qkv<<<dim3(18, 128), dim3(256), 0, stream>>>(xh, xl, wqh, wql, qhm, qlm, km, v0m);
  k_veins<<<dim3(768), dim3(256), 0, stream>>>(km, v0m, wvh, bv, vm);
  k_segments<<<dim3(96), dim3(256), 0, stream>>>(km, vm, Ksh, Ksl, Vt);
  k_attn2<<<dim3(32, 96), dim3(256), 0, stream>>>(qhm, qlm, km, vm, Ksh, Ksl, Vt, outp);
  k_gemm_proj<<<dim3(6, 128), dim3(256), 0, stream>>>(outp, wpb, out);
}

// Round 5
// 465.871 us; speedup vs baseline: 2.4142x; 1.2831x over previous
//
#include <hip/hip_runtime.h>

// FixSetLinearAttention: B=8 T=2048 C=768 NH=12 hs=64 Lmin=16, 255 segments + tail.
// R5: all-fp16 pipeline (fp16 u=2^-11 makes single-pass GEMMs exp-safe: logit err
// ~0.002). qkv/proj use global_load_lds width-16 with pre-swizzled global source +
// linear LDS + XOR read. k stored fp16 (km f32 eliminated). attn2 single-Ks fp16.

typedef float  f32x4  __attribute__((ext_vector_type(4)));
typedef _Float16 half8 __attribute__((ext_vector_type(8)));
typedef _Float16 half4 __attribute__((ext_vector_type(4)));

#define DEV __device__ __forceinline__
#define MFMA16(a, b, c) __builtin_amdgcn_mfma_f32_16x16x32_f16((a), (b), (c), 0, 0, 0)
#define GLOAD16(gp, lp)                                                  \
  __builtin_amdgcn_global_load_lds(                                      \
      (const __attribute__((address_space(1))) unsigned int*)(gp),       \
      (__attribute__((address_space(3))) unsigned int*)(lp), 16, 0, 0)

// ---------------- prep: f32 -> fp16 ----------------
__global__ __launch_bounds__(256) void k_cast16(const float* __restrict__ in,
                                                _Float16* __restrict__ outh, int n4) {
  int i = blockIdx.x * 256 + threadIdx.x;
  if (i >= n4) return;
  f32x4 v = ((const f32x4*)in)[i];
  half4 o;
#pragma unroll
  for (int c = 0; c < 4; ++c) o[c] = (_Float16)v[c];
  ((half4*)outh)[i] = o;
}

// ---------------- qkv GEMM: C = A @ B^T, fp16 single pass ----------------
// A = x16 (16384 x 768), B = wq16 (2304 x 768). Scattered epilogue into q/k/v0
// fp16 in (b,h,t,d) layout.
__global__ __launch_bounds__(256, 3) void k_gemm_qkv(
    const _Float16* __restrict__ A16, const _Float16* __restrict__ B16,
    _Float16* __restrict__ qo, _Float16* __restrict__ ko, _Float16* __restrict__ v0o) {
  __shared__ _Float16 sA[128][64], sB[128][64];
  const int K = 768;
  int tid = threadIdx.x, lane = tid & 63, wave = tid >> 6;
  int l15 = lane & 15, g = lane >> 4;
  int wr = wave >> 1, wc = wave & 1;
  int n0 = blockIdx.x * 128, m0 = blockIdx.y * 128;
  f32x4 acc[4][4];
#pragma unroll
  for (int a = 0; a < 4; ++a)
#pragma unroll
    for (int b = 0; b < 4; ++b) acc[a][b] = f32x4{0.f, 0.f, 0.f, 0.f};
  int rsel = lane >> 3;            // row within 8-row group; row&7 == rsel
  int csel = (lane & 7) ^ rsel;    // pre-swizzled source chunk
  for (int k0 = 0; k0 < K; k0 += 64) {
#pragma unroll
    for (int r = 0; r < 4; ++r) {
      int row = wave * 32 + r * 8 + rsel;
      GLOAD16(&A16[(size_t)(m0 + row) * K + k0 + csel * 8], &sA[wave * 32 + r * 8][0]);
      GLOAD16(&B16[(size_t)(n0 + row) * K + k0 + csel * 8], &sB[wave * 32 + r * 8][0]);
    }
    __syncthreads();
#pragma unroll
    for (int kk = 0; kk < 2; ++kk) {
      int kc = kk * 4 + g;
      int cc = ((kc ^ (l15 & 7)) << 3);
      half8 af[4], bf[4];
#pragma unroll
      for (int mf = 0; mf < 4; ++mf) af[mf] = *(const half8*)&sA[wr * 64 + mf * 16 + l15][cc];
#pragma unroll
      for (int nf = 0; nf < 4; ++nf) bf[nf] = *(const half8*)&sB[wc * 64 + nf * 16 + l15][cc];
#pragma unroll
      for (int mf = 0; mf < 4; ++mf)
#pragma unroll
        for (int nf = 0; nf < 4; ++nf)
          acc[mf][nf] = MFMA16(af[mf], bf[nf], acc[mf][nf]);
    }
    __syncthreads();
  }
  int sec = n0 / 768;
  int nb = n0 - sec * 768;
#pragma unroll
  for (int mf = 0; mf < 4; ++mf)
#pragma unroll
    for (int nf = 0; nf < 4; ++nf)
#pragma unroll
      for (int r = 0; r < 4; ++r) {
        int m = m0 + wr * 64 + mf * 16 + (g << 2) + r;
        int n = nb + wc * 64 + nf * 16 + l15;
        int b = m >> 11, t = m & 2047;
        int h = n >> 6, d = n & 63;
        size_t idx = (((size_t)b * 12 + h) * 2048 + t) * 64 + d;
        _Float16 val = (_Float16)acc[mf][nf][r];
        if (sec == 0) qo[idx] = val;
        else if (sec == 1) ko[idx] = val;
        else v0o[idx] = val;
      }
}

// ---------------- v = (k (x) v0) @ Wv^T + bv  (fp16, reg v0, B prefetch) ----------------
__global__ __launch_bounds__(256, 3) void k_veins(
    const _Float16* __restrict__ kh, const _Float16* __restrict__ v0g,
    const _Float16* __restrict__ Wvh, const float* __restrict__ bv,
    _Float16* __restrict__ vout) {
  __shared__ _Float16 ks[256][72];  // 36 KB
  int tid = threadIdx.x, lane = tid & 63, wave = tid >> 6;
  int l15 = lane & 15, g = lane >> 4, g8 = g << 3;
  size_t row0 = (size_t)blockIdx.x * 256;
#pragma unroll
  for (int r = 0; r < 8; ++r) {
    int row = (tid >> 3) + r * 32;
    int c8 = (tid & 7) << 3;
    *(half8*)&ks[row][c8] = *(const half8*)&kh[(row0 + row) * 64 + c8];
  }
  half8 v0r[4][2];
#pragma unroll
  for (int mf = 0; mf < 4; ++mf) {
    size_t rb = (row0 + wave * 64 + mf * 16 + l15) * 64;
#pragma unroll
    for (int kk = 0; kk < 2; ++kk)
      v0r[mf][kk] = *(const half8*)&v0g[rb + kk * 32 + g8];
  }
  f32x4 acc[4][4];
#pragma unroll
  for (int a = 0; a < 4; ++a)
#pragma unroll
    for (int b = 0; b < 4; ++b) acc[a][b] = f32x4{0.f, 0.f, 0.f, 0.f};

  const _Float16* W0 = Wvh + (size_t)l15 * 4096 + g8;
  half8 bA[4], bB[4];
#pragma unroll
  for (int nf = 0; nf < 4; ++nf) bA[nf] = *(const half8*)&W0[(size_t)nf * 16 * 4096];
  __syncthreads();
  int r0 = wave * 64 + l15;
  for (int i = 0; i < 64; ++i) {
#pragma unroll
    for (int nf = 0; nf < 4; ++nf)
      bB[nf] = *(const half8*)&W0[(size_t)nf * 16 * 4096 + i * 64 + 32];
    _Float16 kv0 = ks[r0][i];
    _Float16 kv1 = ks[r0 + 16][i];
    _Float16 kv2 = ks[r0 + 32][i];
    _Float16 kv3 = ks[r0 + 48][i];
    {
      half8 a0 = v0r[0][0] * kv0, a1 = v0r[1][0] * kv1;
      half8 a2 = v0r[2][0] * kv2, a3 = v0r[3][0] * kv3;
#pragma unroll
      for (int nf = 0; nf < 4; ++nf) {
        acc[0][nf] = MFMA16(a0, bA[nf], acc[0][nf]);
        acc[1][nf] = MFMA16(a1, bA[nf], acc[1][nf]);
        acc[2][nf] = MFMA16(a2, bA[nf], acc[2][nf]);
        acc[3][nf] = MFMA16(a3, bA[nf], acc[3][nf]);
      }
    }
    if (i < 63) {
#pragma unroll
      for (int nf = 0; nf < 4; ++nf)
        bA[nf] = *(const half8*)&W0[(size_t)nf * 16 * 4096 + (i + 1) * 64];
    }
    {
      half8 a0 = v0r[0][1] * kv0, a1 = v0r[1][1] * kv1;
      half8 a2 = v0r[2][1] * kv2, a3 = v0r[3][1] * kv3;
#pragma unroll
      for (int nf = 0; nf < 4; ++nf) {
        acc[0][nf] = MFMA16(a0, bB[nf], acc[0][nf]);
        acc[1][nf] = MFMA16(a1, bB[nf], acc[1][nf]);
        acc[2][nf] = MFMA16(a2, bB[nf], acc[2][nf]);
        acc[3][nf] = MFMA16(a3, bB[nf], acc[3][nf]);
      }
    }
  }
#pragma unroll
  for (int mf = 0; mf < 4; ++mf)
#pragma unroll
    for (int nf = 0; nf < 4; ++nf) {
      int e = (nf << 4) + l15;
      float bve = bv[e];
#pragma unroll
      for (int r = 0; r < 4; ++r) {
        int row = wave * 64 + mf * 16 + (g << 2) + r;
        vout[(row0 + row) * 64 + e] = (_Float16)(acc[mf][nf][r] + bve);
      }
    }
}

// ---------------- segment sums -> Ks fp16 [bh][256][64], Vt fp16 [bh][64][256] ----------------
__global__ __launch_bounds__(256) void k_segments(
    const _Float16* __restrict__ kmat, const _Float16* __restrict__ vmat,
    _Float16* __restrict__ Ks, _Float16* __restrict__ Vt) {
  __shared__ float Ls[255][64];
  int bh = blockIdx.x, tid = threadIdx.x;
  size_t bh2048 = (size_t)bh * 2048;
  // ---- K ----
  for (int task = tid; task < 8192; task += 256) {
    int seg = task >> 6, d = task & 63;
    const _Float16* p = kmat + (bh2048 + seg * 16) * 64 + d;
    float s = 0.f;
#pragma unroll
    for (int u = 0; u < 16; ++u) s += (float)p[u * 64];
    Ls[seg][d] = s;
  }
  __syncthreads();
  {
    int bprev = 0, bcur = 128, cnt = 64;
    for (int lev = 1; lev < 8; ++lev) {
      for (int task = tid; task < cnt * 64; task += 256) {
        int i = task >> 6, d = task & 63;
        Ls[bcur + i][d] = Ls[bprev + 2 * i][d] + Ls[bprev + 2 * i + 1][d];
      }
      __syncthreads();
      bprev = bcur; bcur += cnt; cnt >>= 1;
    }
  }
  for (int task = tid; task < 16384; task += 256) {
    int seg = task >> 6;
    float v = (seg < 255) ? Ls[seg][task & 63] : 0.f;
    Ks[(size_t)bh * 16384 + task] = (_Float16)v;
  }
  __syncthreads();
  // ---- V ----
  for (int task = tid; task < 8192; task += 256) {
    int seg = task >> 6, d = task & 63;
    const _Float16* p = vmat + (bh2048 + seg * 16) * 64 + d;
    float s = 0.f;
#pragma unroll
    for (int u = 0; u < 16; ++u) s += (float)p[u * 64];
    Ls[seg][d] = s;
  }
  __syncthreads();
  {
    int bprev = 0, bcur = 128, cnt = 64;
    for (int lev = 1; lev < 8; ++lev) {
      for (int task = tid; task < cnt * 64; task += 256) {
        int i = task >> 6, d = task & 63;
        Ls[bcur + i][d] = Ls[bprev + 2 * i][d] + Ls[bprev + 2 * i + 1][d];
      }
      __syncthreads();
      bprev = bcur; bcur += cnt; cnt >>= 1;
    }
  }
  for (int task = tid; task < 16384; task += 256) {
    int d = task >> 8, seg = task & 255;
    float v = (seg < 255) ? Ls[seg][d] : 0.f;
    Vt[(size_t)bh * 16384 + task] = (_Float16)v;
  }
}

// ---------------- MFMA attention (fp16): block = (bh, 64-tok tile), 4 waves ----------------
__global__ __launch_bounds__(256) void k_attn2(
    const _Float16* __restrict__ qm, const _Float16* __restrict__ km,
    const _Float16* __restrict__ vm,
    const _Float16* __restrict__ Ks, const _Float16* __restrict__ Vt,
    _Float16* __restrict__ outp) {
  __shared__ __align__(16) _Float16 P[4][16][296];
  __shared__ __align__(16) _Float16 tK[4][16][72];
  __shared__ __align__(16) _Float16 tV[4][16][72];
  int tid = threadIdx.x, lane = tid & 63, wave = tid >> 6;
  int orig = blockIdx.y * 32 + blockIdx.x;
  int wg = (orig & 7) * 384 + (orig >> 3);  // XCD-chunked swizzle (3072 = 8*384)
  int tile = wg & 31, bh = wg >> 5;
  int t0 = tile * 64, tw0 = t0 + wave * 16;
  size_t bh2048 = (size_t)bh * 2048;
  int l15 = lane & 15, g = lane >> 4, g8 = g << 3;

  // per-wave tail prefixes (lane = d)
  {
    const _Float16* kp = km + (bh2048 + tw0) * 64 + lane;
    const _Float16* vp = vm + (bh2048 + tw0) * 64 + lane;
    float ka = 0.f, va = 0.f;
#pragma unroll
    for (int t = 0; t < 16; ++t) {
      ka += (float)kp[t * 64];
      va += (float)vp[t * 64];
      tK[wave][t][lane] = (_Float16)ka;
      tV[wave][t][lane] = (_Float16)va;
    }
  }
  // Q fragments
  half8 qf[2];
  {
    const _Float16* qp = qm + (bh2048 + tw0 + l15) * 64 + g8;
    qf[0] = *(const half8*)qp;
    qf[1] = *(const half8*)(qp + 32);
  }
  // validity masks
  unsigned mA = 0, mE = 0;
#pragma unroll
  for (int nf = 0; nf < 16; ++nf) {
    int seg = nf * 16 + l15;
    if (seg < 255) {
      int m = 256 - seg;
      int cl = 32 - __clz(m - 1);
      int lev = 8 - cl;
      int rdx = (seg - (256 - (256 >> lev)) + 1) * (16 << lev) - 1;
      if (rdx < tw0) mA |= 1u << nf;
      else if (rdx == tw0 + 15) mE |= 1u << nf;
    }
  }
  unsigned mAny = mA | mE;
  unsigned pmask = 0;
#pragma unroll
  for (int ks = 0; ks < 8; ++ks)
    if (__any((int)((mAny >> (2 * ks)) & 3u))) pmask |= 1u << ks;

  // ---- QK^T ----
  f32x4 acc[17];
#pragma unroll
  for (int i = 0; i < 17; ++i) acc[i] = f32x4{0.f, 0.f, 0.f, 0.f};
  const _Float16* KsB = Ks + (size_t)bh * 16384;
#pragma unroll
  for (int ks = 0; ks < 8; ++ks) {
    if ((pmask >> ks) & 1) {
      const _Float16* ph = KsB + (size_t)(ks * 32 + l15) * 64 + g8;
      half8 h00 = *(const half8*)ph;
      half8 h01 = *(const half8*)(ph + 32);
      half8 h10 = *(const half8*)(ph + 1024);
      half8 h11 = *(const half8*)(ph + 1056);
      acc[2 * ks] = MFMA16(qf[0], h00, acc[2 * ks]);
      acc[2 * ks] = MFMA16(qf[1], h01, acc[2 * ks]);
      acc[2 * ks + 1] = MFMA16(qf[0], h10, acc[2 * ks + 1]);
      acc[2 * ks + 1] = MFMA16(qf[1], h11, acc[2 * ks + 1]);
    }
  }
  {  // tail fragment (nf=16)
    const _Float16* tp = &tK[wave][l15][g8];
    half8 t0f = *(const half8*)tp;
    half8 t1f = *(const half8*)(tp + 32);
    acc[16] = MFMA16(qf[0], t0f, acc[16]);
    acc[16] = MFMA16(qf[1], t1f, acc[16]);
  }

  // ---- softmax (f32) ----
  const float scale = 0.125f;
  float mx[4], sm[4], et[4];
#pragma unroll
  for (int r = 0; r < 4; ++r) {
    int tr = g * 4 + r;
    mx[r] = (l15 == tr) ? acc[16][r] * scale : -3.0e38f;
  }
#pragma unroll
  for (int nf = 0; nf < 16; ++nf) {
    bool bA = (mA >> nf) & 1, bE = (mE >> nf) & 1;
#pragma unroll
    for (int r = 0; r < 4; ++r) {
      bool u = bA || (bE && g == 3 && r == 3);
      if (u) mx[r] = fmaxf(mx[r], acc[nf][r] * scale);
    }
  }
#pragma unroll
  for (int off = 1; off < 16; off <<= 1)
#pragma unroll
    for (int r = 0; r < 4; ++r) mx[r] = fmaxf(mx[r], __shfl_xor(mx[r], off));
#pragma unroll
  for (int r = 0; r < 4; ++r) {
    int tr = g * 4 + r;
    et[r] = (l15 == tr) ? __expf(acc[16][r] * scale - mx[r]) : 0.f;
    sm[r] = et[r];
  }
#pragma unroll
  for (int ks = 0; ks < 8; ++ks) {
    if ((pmask >> ks) & 1) {
#pragma unroll
      for (int f = 0; f < 2; ++f) {
        int nf = 2 * ks + f;
        bool bA = (mA >> nf) & 1, bE = (mE >> nf) & 1;
#pragma unroll
        for (int r = 0; r < 4; ++r) {
          bool u = bA || (bE && g == 3 && r == 3);
          float e = u ? __expf(acc[nf][r] * scale - mx[r]) : 0.f;
          acc[nf][r] = e;
          sm[r] += e;
        }
      }
    }
  }
#pragma unroll
  for (int off = 1; off < 16; off <<= 1)
#pragma unroll
    for (int r = 0; r < 4; ++r) sm[r] += __shfl_xor(sm[r], off);
  float inv[4];
#pragma unroll
  for (int r = 0; r < 4; ++r) inv[r] = 1.f / sm[r];

  // ---- P writes (per-wave LDS) ----
  half8 zz = {};
  *(half8*)&P[wave][lane >> 2][256 + (lane & 3) * 8] = zz;
#pragma unroll
  for (int nf = 0; nf < 16; ++nf)
#pragma unroll
    for (int r = 0; r < 4; ++r)
      P[wave][g * 4 + r][nf * 16 + l15] = (_Float16)(acc[nf][r] * inv[r]);
#pragma unroll
  for (int r = 0; r < 4; ++r)
    if (l15 == g * 4 + r) P[wave][l15][256 + l15] = (_Float16)(et[r] * inv[r]);

  // ---- PV ----
  f32x4 oa[4];
#pragma unroll
  for (int i = 0; i < 4; ++i) oa[i] = f32x4{0.f, 0.f, 0.f, 0.f};
  const _Float16* VB = Vt + (size_t)bh * 16384;
#pragma unroll
  for (int ks = 0; ks < 8; ++ks) {
    if ((pmask >> ks) & 1) {
      half8 pa = *(const half8*)&P[wave][l15][ks * 32 + g8];
#pragma unroll
      for (int n2 = 0; n2 < 4; ++n2) {
        half8 vb = *(const half8*)(VB + (size_t)(n2 * 16 + l15) * 256 + ks * 32 + g8);
        oa[n2] = MFMA16(pa, vb, oa[n2]);
      }
    }
  }
  {  // tail k-step
    half8 pa = *(const half8*)&P[wave][l15][256 + g8];
    int jb = (g & 1) * 8;
#pragma unroll
    for (int n2 = 0; n2 < 4; ++n2) {
      half8 vt;
#pragma unroll
      for (int jj = 0; jj < 8; ++jj) vt[jj] = tV[wave][jb + jj][n2 * 16 + l15];
      oa[n2] = MFMA16(pa, vt, oa[n2]);
    }
  }
  // ---- output ----
  int b = bh / 12, h = bh - b * 12;
  size_t obase = ((size_t)b * 2048 + tw0) * 768 + h * 64;
#pragma unroll
  for (int n2 = 0; n2 < 4; ++n2)
#pragma unroll
    for (int r = 0; r < 4; ++r)
      outp[obase + (size_t)(g * 4 + r) * 768 + n2 * 16 + l15] = (_Float16)oa[n2][r];
}

// ---------------- proj GEMM: d_out = out_pre @ Wproj^T (fp16, gload staging) ----------------
__global__ __launch_bounds__(256, 3) void k_gemm_proj(
    const _Float16* __restrict__ A16, const _Float16* __restrict__ B16,
    float* __restrict__ C) {
  __shared__ _Float16 sA[128][64], sB[128][64];
  const int K = 768;
  int tid = threadIdx.x, lane = tid & 63, wave = tid >> 6;
  int l15 = lane & 15, g = lane >> 4;
  int wr = wave >> 1, wc = wave & 1;
  int n0 = blockIdx.x * 128, m0 = blockIdx.y * 128;
  f32x4 acc[4][4];
#pragma unroll
  for (int a = 0; a < 4; ++a)
#pragma unroll
    for (int b = 0; b < 4; ++b) acc[a][b] = f32x4{0.f, 0.f, 0.f, 0.f};
  int rsel = lane >> 3;
  int csel = (lane & 7) ^ rsel;
  for (int k0 = 0; k0 < K; k0 += 64) {
#pragma unroll
    for (int r = 0; r < 4; ++r) {
      int row = wave * 32 + r * 8 + rsel;
      GLOAD16(&A16[(size_t)(m0 + row) * K + k0 + csel * 8], &sA[wave * 32 + r * 8][0]);
      GLOAD16(&B16[(size_t)(n0 + row) * K + k0 + csel * 8], &sB[wave * 32 + r * 8][0]);
    }
    __syncthreads();
#pragma unroll
    for (int kk = 0; kk < 2; ++kk) {
      int kc = kk * 4 + g;
      int cc = ((kc ^ (l15 & 7)) << 3);
      half8 af[4], bf[4];
#pragma unroll
      for (int mf = 0; mf < 4; ++mf) af[mf] = *(const half8*)&sA[wr * 64 + mf * 16 + l15][cc];
#pragma unroll
      for (int nf = 0; nf < 4; ++nf) bf[nf] = *(const half8*)&sB[wc * 64 + nf * 16 + l15][cc];
#pragma unroll
      for (int mf = 0; mf < 4; ++mf)
#pragma unroll
        for (int nf = 0; nf < 4; ++nf)
          acc[mf][nf] = MFMA16(af[mf], bf[nf], acc[mf][nf]);
    }
    __syncthreads();
  }
#pragma unroll
  for (int mf = 0; mf < 4; ++mf)
#pragma unroll
    for (int nf = 0; nf < 4; ++nf)
#pragma unroll
      for (int r = 0; r < 4; ++r) {
        int m = m0 + wr * 64 + mf * 16 + (g << 2) + r;
        int n = n0 + wc * 64 + nf * 16 + l15;
        C[(size_t)m * 768 + n] = acc[mf][nf][r];
      }
}

// ---------------- host launch ----------------
extern "C" void kernel_launch(void* const* d_in, const int* in_sizes, int n_in,
                              void* d_out, int out_size, void* d_ws, size_t ws_size,
                              hipStream_t stream) {
  const float* x = (const float*)d_in[0];
  const float* Wqkv = (const float*)d_in[1];
  const float* Wproj = (const float*)d_in[2];
  const float* Wv = (const float*)d_in[3];
  const float* bv = (const float*)d_in[4];
  float* out = (float*)d_out;
  char* ws = (char*)d_ws;
  size_t off = 0;
  auto alloc = [&](size_t bytes) -> void* {
    void* p = (void*)(ws + off);
    off += (bytes + 255) & ~(size_t)255;
    return p;
  };
  _Float16* x16  = (_Float16*)alloc(12582912ull * 2);
  _Float16* wq16 = (_Float16*)alloc(1769472ull * 2);
  _Float16* wv16 = (_Float16*)alloc(262144ull * 2);
  _Float16* wp16 = (_Float16*)alloc(589824ull * 2);
  _Float16* q16  = (_Float16*)alloc(12582912ull * 2);
  _Float16* k16  = (_Float16*)alloc(12582912ull * 2);
  _Float16* v016 = (_Float16*)alloc(12582912ull * 2);
  _Float16* vm16 = (_Float16*)alloc(12582912ull * 2);
  _Float16* Ks   = (_Float16*)alloc(1572864ull * 2);
  _Float16* Vt   = (_Float16*)alloc(1572864ull * 2);
  _Float16* outp = (_Float16*)alloc(12582912ull * 2);

  k_cast16<<<dim3(12288), dim3(256), 0, stream>>>(x, x16, 3145728);
  k_cast16<<<dim3(1728), dim3(256), 0, stream>>>(Wqkv, wq16, 442368);
  k_cast16<<<dim3(256), dim3(256), 0, stream>>>(Wv, wv16, 65536);
  k_cast16<<<dim3(576), dim3(256), 0, stream>>>(Wproj, wp16, 147456);
  k_gemm_qkv<<<dim3(18, 128), dim3(256), 0, stream>>>(x16, wq16, q16, k16, v016);
  k_veins<<<dim3(768), dim3(256), 0, stream>>>(k16, v016, wv16, bv, vm16);
  k_segments<<<dim3(96), dim3(256), 0, stream>>>(k16, vm16, Ks, Vt);
  k_attn2<<<dim3(32, 96), dim3(256), 0, stream>>>(q16, k16, vm16, Ks, Vt, outp);
  k_gemm_proj<<<dim3(6, 128), dim3(256), 0, stream>>>(outp, wp16, out);
}